// Round 11
// baseline (450.261 us; speedup 1.0000x reference)
//
#include <hip/hip_runtime.h>

// S,P,M=(128,2048,64), NC,NB=(16,8), H,W=512, EXTENT=12, EPS=1e-9
#define NS   128
#define NP   2048
#define NM   64
#define NCYL 16
#define NBOX 8
#define IH   512
#define IW   512
#define NPIX (IH*IW)
#define FEXT 12.0f
#define FEPS 1e-9f
#define PXSCALE ((float)IW / (2.0f * FEXT))
#define PRUNE_MARGIN 0.05f
#define SPT  8      // sources per thread
#define NTILE 256   // 16x16 grid of 32x32-pixel tiles
#define GSPLIT 8    // pass-2 blocks per tile
#define CHUNK 256u  // max records per descriptor (bounds per-lane work in pass 2)

__device__ __forceinline__ float frcp(float x)   { return __builtin_amdgcn_rcpf(x); }
__device__ __forceinline__ float frsq(float x)   { return __builtin_amdgcn_rsqf(x); }
__device__ __forceinline__ float fsqrt_(float x) { return __builtin_amdgcn_sqrtf(x); }
__device__ __forceinline__ float clamp01(float x){ return fminf(fmaxf(x, 0.0f), 1.0f); }

// ---------------- Pre-pass A: per-mirror bounding sphere of transformed points
__global__ __launch_bounds__(256) void mirror_bounds_kernel(
    const float* __restrict__ mpts, const float* __restrict__ mpos,
    const float* __restrict__ mrot, float4* __restrict__ bounds)
{
    const int m = blockIdx.x;
    const int t = threadIdx.x;
    float R0 = mrot[m*9+0], R1 = mrot[m*9+1], R2 = mrot[m*9+2];
    float R3 = mrot[m*9+3], R4 = mrot[m*9+4], R5 = mrot[m*9+5];
    float R6 = mrot[m*9+6], R7 = mrot[m*9+7], R8 = mrot[m*9+8];
    float posx = mpos[m*3+0], posy = mpos[m*3+1], posz = mpos[m*3+2];

    float mnx = 1e30f, mny = 1e30f, mnz = 1e30f;
    float mxx = -1e30f, mxy = -1e30f, mxz = -1e30f;
    for (int i = t; i < NP; i += 256) {
        long id = ((long)m * NP + i) * 3;
        float px = mpts[id+0], py = mpts[id+1], pz = mpts[id+2];
        float tx = R0*px + R1*py + R2*pz + posx;
        float ty = R3*px + R4*py + R5*pz + posy;
        float tz = R6*px + R7*py + R8*pz + posz;
        mnx = fminf(mnx, tx); mny = fminf(mny, ty); mnz = fminf(mnz, tz);
        mxx = fmaxf(mxx, tx); mxy = fmaxf(mxy, ty); mxz = fmaxf(mxz, tz);
    }
    __shared__ float red[6][256];
    red[0][t] = mnx; red[1][t] = mny; red[2][t] = mnz;
    red[3][t] = mxx; red[4][t] = mxy; red[5][t] = mxz;
    __syncthreads();
    for (int off = 128; off > 0; off >>= 1) {
        if (t < off) {
            red[0][t] = fminf(red[0][t], red[0][t+off]);
            red[1][t] = fminf(red[1][t], red[1][t+off]);
            red[2][t] = fminf(red[2][t], red[2][t+off]);
            red[3][t] = fmaxf(red[3][t], red[3][t+off]);
            red[4][t] = fmaxf(red[4][t], red[4][t+off]);
            red[5][t] = fmaxf(red[5][t], red[5][t+off]);
        }
        __syncthreads();
    }
    if (t == 0) {
        float cx = 0.5f*(red[0][0]+red[3][0]);
        float cy = 0.5f*(red[1][0]+red[4][0]);
        float cz = 0.5f*(red[2][0]+red[5][0]);
        float hx = 0.5f*(red[3][0]-red[0][0]);
        float hy = 0.5f*(red[4][0]-red[1][0]);
        float hz = 0.5f*(red[5][0]-red[2][0]);
        float r  = sqrtf(hx*hx + hy*hy + hz*hz);
        bounds[m] = make_float4(cx, cy, cz, r);
    }
}

// ---------------- Pre-pass B: per-(mirror,source) occluder mask (conservative)
__global__ __launch_bounds__(256) void mask_kernel(
    const float* __restrict__ sources,
    const float* __restrict__ cp1g, const float* __restrict__ cp2g,
    const float* __restrict__ crad,
    const float* __restrict__ bp1g, const float* __restrict__ bp2g,
    const float4* __restrict__ bounds, unsigned* __restrict__ masks)
{
    int pair = blockIdx.x * 256 + threadIdx.x;
    if (pair >= NM * NS) return;
    int m = pair / NS;
    int s = pair - m * NS;

    float4 bd = bounds[m];
    float cx = bd.x, cy = bd.y, cz = bd.z;
    float rm = bd.w + PRUNE_MARGIN;
    float sx = sources[s*3+0], sy = sources[s*3+1], sz = sources[s*3+2];

    float d1x = sx - cx, d1y = sy - cy, d1z = sz - cz;
    float a = d1x*d1x + d1y*d1y + d1z*d1z;

    unsigned mask = 0;

    for (int c = 0; c < NCYL; c++) {
        float p2x = cp1g[c*3+0], p2y = cp1g[c*3+1], p2z = cp1g[c*3+2];
        float d2x = cp2g[c*3+0] - p2x, d2y = cp2g[c*3+1] - p2y, d2z = cp2g[c*3+2] - p2z;
        float rx = cx - p2x, ry = cy - p2y, rz = cz - p2z;
        float e = d2x*d2x + d2y*d2y + d2z*d2z;
        float f = d2x*rx + d2y*ry + d2z*rz;
        float cc = d1x*rx + d1y*ry + d1z*rz;
        float b = d1x*d2x + d1y*d2y + d1z*d2z;
        float denom = a*e - b*b;
        float sN = (denom > 1e-6f) ? clamp01((b*f - cc*e) / denom) : 0.0f;
        float tN = (b*sN + f) / e;
        if (tN < 0.0f)      { tN = 0.0f; sN = clamp01(-cc / a); }
        else if (tN > 1.0f) { tN = 1.0f; sN = clamp01((b - cc) / a); }
        float gx = (cx + d1x*sN) - (p2x + d2x*tN);
        float gy = (cy + d1y*sN) - (p2y + d2y*tN);
        float gz = (cz + d1z*sN) - (p2z + d2z*tN);
        float dist2 = gx*gx + gy*gy + gz*gz;
        float thr = crad[c] + rm;
        if (dist2 <= thr*thr) mask |= (1u << c);
    }

    float ivx = 1.0f / ((fabsf(d1x) < FEPS) ? FEPS : d1x);
    float ivy = 1.0f / ((fabsf(d1y) < FEPS) ? FEPS : d1y);
    float ivz = 1.0f / ((fabsf(d1z) < FEPS) ? FEPS : d1z);
    for (int b = 0; b < NBOX; b++) {
        float lx = bp1g[b*3+0] - rm, ly = bp1g[b*3+1] - rm, lz = bp1g[b*3+2] - rm;
        float hx = bp2g[b*3+0] + rm, hy = bp2g[b*3+1] + rm, hz = bp2g[b*3+2] + rm;
        float t0x = (lx - cx) * ivx, t1x = (hx - cx) * ivx;
        float t0y = (ly - cy) * ivy, t1y = (hy - cy) * ivy;
        float t0z = (lz - cz) * ivz, t1z = (hz - cz) * ivz;
        float tmin = fmaxf(fmaxf(fminf(t0x,t1x), fminf(t0y,t1y)), fminf(t0z,t1z));
        float tmax = fminf(fminf(fmaxf(t0x,t1x), fmaxf(t0y,t1y)), fmaxf(t0z,t1z));
        if (fmaxf(tmin, 0.0f) <= fminf(tmax, 1.0f)) mask |= (1u << (16 + b));
    }

    masks[pair] = mask;
}

// ================= BINNING PIPELINE (pass 1): rays -> tile-grouped records
__global__ __launch_bounds__(256) void render_bin_kernel(
    const float* __restrict__ sources, const float* __restrict__ mpts,
    const float* __restrict__ mnrm,    const float* __restrict__ mpos,
    const float* __restrict__ mrot,
    const float* __restrict__ cp1g, const float* __restrict__ cp2g,
    const float* __restrict__ crad, const float* __restrict__ bp1g,
    const float* __restrict__ bp2g, const float* __restrict__ spp,
    const float* __restrict__ spn,  const unsigned* __restrict__ masks,
    unsigned* __restrict__ arena, uint2* __restrict__ desc,
    unsigned* __restrict__ desc_cnt, unsigned* __restrict__ galloc,
    float* __restrict__ img_direct, int maxd)
{
    __shared__ float4 s_cyl[NCYL][2];
    __shared__ float4 s_box[NBOX][2];
    __shared__ unsigned s_cnt[NTILE];
    __shared__ unsigned s_inc[NTILE];
    __shared__ unsigned s_scratch[256 * SPT];
    __shared__ unsigned s_base;
    __shared__ unsigned s_of[64][2];
    __shared__ unsigned s_ofn;

    const int t  = threadIdx.x;
    const int n  = blockIdx.x * 256 + t;
    const int s0 = blockIdx.y * SPT;
    const int m  = blockIdx.z;

    const long idx = ((long)m * NP + n) * 3;
    float px = mpts[idx+0], py = mpts[idx+1], pz = mpts[idx+2];
    float nx = mnrm[idx+0], ny = mnrm[idx+1], nz = mnrm[idx+2];

    s_cnt[t] = 0;   // 256 threads == NTILE
    if (t == 0) s_ofn = 0;
    if (t < NCYL) {
        float p1x = cp1g[t*3+0], p1y = cp1g[t*3+1], p1z = cp1g[t*3+2];
        float axx = cp2g[t*3+0] - p1x;
        float axy = cp2g[t*3+1] - p1y;
        float axz = cp2g[t*3+2] - p1z;
        float L   = sqrtf(axx*axx + axy*axy + axz*axz);
        float inv = 1.0f / (L + FEPS);
        float r   = crad[t];
        s_cyl[t][0] = make_float4(p1x, p1y, p1z, L);
        s_cyl[t][1] = make_float4(axx*inv, axy*inv, axz*inv, r*r);
    } else if (t < NCYL + NBOX) {
        int b = t - NCYL;
        s_box[b][0] = make_float4(bp1g[b*3+0], bp1g[b*3+1], bp1g[b*3+2], 0.0f);
        s_box[b][1] = make_float4(bp2g[b*3+0], bp2g[b*3+1], bp2g[b*3+2], 0.0f);
    }
    __syncthreads();

    float R0 = mrot[m*9+0], R1 = mrot[m*9+1], R2 = mrot[m*9+2];
    float R3 = mrot[m*9+3], R4 = mrot[m*9+4], R5 = mrot[m*9+5];
    float R6 = mrot[m*9+6], R7 = mrot[m*9+7], R8 = mrot[m*9+8];
    float posx = mpos[m*3+0], posy = mpos[m*3+1], posz = mpos[m*3+2];
    float sppx = spp[0], sppy = spp[1], sppz = spp[2];
    float spnx = spn[0], spny = spn[1], spnz = spn[2];

    float tpx = R0*px + R1*py + R2*pz + posx;
    float tpy = R3*px + R4*py + R5*pz + posy;
    float tpz = R6*px + R7*py + R8*pz + posz;
    float tnx = R0*nx + R1*ny + R2*nz;
    float tny = R3*nx + R4*ny + R5*nz;
    float tnz = R6*nx + R7*ny + R8*nz;

    float num = (sppx-tpx)*spnx + (sppy-tpy)*spny + (sppz-tpz)*spnz;

    unsigned rec[SPT];
    unsigned rank[SPT];
    int      tileid[SPT];
    unsigned vmask = 0;

    #pragma unroll
    for (int j = 0; j < SPT; j++) {
        const int s = s0 + j;
        float sx = sources[s*3+0], sy = sources[s*3+1], sz = sources[s*3+2];

        float dx = tpx - sx, dy = tpy - sy, dz = tpz - sz;
        float il = frsq(dx*dx + dy*dy + dz*dz);
        dx *= il; dy *= il; dz *= il;
        float ux = -dx, uy = -dy, uz = -dz;

        unsigned pm = masks[(unsigned)m * NS + (unsigned)s];
        pm = __builtin_amdgcn_readfirstlane(pm);
        unsigned cmask = pm & 0xFFFFu;
        unsigned bmask = (pm >> 16) & 0xFFu;

        bool hit = false;

        while (cmask) {
            int c = __builtin_ctz(cmask);
            cmask &= cmask - 1;
            float4 c0 = s_cyl[c][0];
            float4 c1 = s_cyl[c][1];
            float ocx = tpx - c0.x, ocy = tpy - c0.y, ocz = tpz - c0.z;
            float oa  = ocx*c1.x + ocy*c1.y + ocz*c1.z;
            float Cc  = ocx*ocx + ocy*ocy + ocz*ocz - oa*oa - c1.w;
            float ua  = ux*c1.x + uy*c1.y + uz*c1.z;
            float ocu = ux*ocx + uy*ocy + uz*ocz;
            float Bh  = fmaf(-oa, ua, ocu);
            float A   = fmaf(-ua, ua, 1.0f);
            float disc = fmaf(Bh, Bh, -(A*Cc));
            float sq   = fsqrt_(fmaxf(disc, 0.0f));
            float Ah   = A + 0.5f*FEPS;
            float q1   = -Bh - sq;
            float q2   = -Bh + sq;
            float oaA  = oa * Ah;
            float LA   = c0.w * Ah;
            float epsA = FEPS * Ah;
            float ax1A = fmaf(q1, ua, oaA);
            float ax2A = fmaf(q2, ua, oaA);
            bool dpos  = disc > 0.0f;
            hit = hit | (dpos & (q1 > epsA) & (ax1A >= 0.0f) & (ax1A <= LA))
                      | (dpos & (q2 > epsA) & (ax2A >= 0.0f) & (ax2A <= LA));
        }

        if (bmask) {
            float ivx = frcp((fabsf(ux) < FEPS) ? FEPS : ux);
            float ivy = frcp((fabsf(uy) < FEPS) ? FEPS : uy);
            float ivz = frcp((fabsf(uz) < FEPS) ? FEPS : uz);
            while (bmask) {
                int b = __builtin_ctz(bmask);
                bmask &= bmask - 1;
                float4 b1 = s_box[b][0];
                float4 b2 = s_box[b][1];
                float t0x = (b1.x - tpx) * ivx, t1x = (b2.x - tpx) * ivx;
                float t0y = (b1.y - tpy) * ivy, t1y = (b2.y - tpy) * ivy;
                float t0z = (b1.z - tpz) * ivz, t1z = (b2.z - tpz) * ivz;
                float tmin = fmaxf(fmaxf(fminf(t0x,t1x), fminf(t0y,t1y)), fminf(t0z,t1z));
                float tmax = fminf(fminf(fmaxf(t0x,t1x), fmaxf(t0y,t1y)), fmaxf(t0z,t1z));
                hit = hit | (tmax >= fmaxf(tmin, FEPS));
            }
        }

        float dn = dx*tnx + dy*tny + dz*tnz;
        float rx = fmaf(-2.0f*dn, tnx, dx);
        float ry = fmaf(-2.0f*dn, tny, dy);
        float rz = fmaf(-2.0f*dn, tnz, dz);
        float cosv  = fabsf(dn);
        float denom = rx*spnx + ry*spny + rz*spnz;
        float tt = num * frcp(denom + FEPS);
        float qx = fmaf(tt, rx, tpx);
        float qy = fmaf(tt, ry, tpy);
        float fx = (qx + FEXT) * PXSCALE;
        float fy = (qy + FEXT) * PXSCALE;
        float fxf = floorf(fx), fyf = floorf(fy);
        bool inb = (fxf >= 0.0f) & (fxf < (float)IW) & (fyf >= 0.0f) & (fyf < (float)IH)
                   & (!hit);
        if (inb) {
            int ix = (int)fxf, iy = (int)fyf;
            unsigned pix = (unsigned)(iy * IW + ix);
            unsigned q = (unsigned)(cosv * 16383.0f + 0.5f);
            if (q > 16383u) q = 16383u;
            rec[j]    = (pix << 14) | q;
            int tl    = ((iy >> 5) << 4) | (ix >> 5);
            tileid[j] = tl;
            rank[j]   = atomicAdd(&s_cnt[tl], 1u);
            vmask    |= (1u << j);
        }
    }
    __syncthreads();

    // Inclusive scan of s_cnt -> s_inc (Hillis-Steele, 256 entries).
    s_inc[t] = s_cnt[t];
    __syncthreads();
    for (int st = 1; st < NTILE; st <<= 1) {
        unsigned v = (t >= st) ? s_inc[t - st] : 0u;
        __syncthreads();
        s_inc[t] += v;
        __syncthreads();
    }
    unsigned total = s_inc[NTILE - 1];
    if (t == 0) s_base = total ? atomicAdd(galloc, total) : 0u;
    __syncthreads();

    // Stage records grouped by tile in LDS.
    #pragma unroll
    for (int j = 0; j < SPT; j++) {
        if (vmask & (1u << j)) {
            int tl = tileid[j];
            unsigned off = s_inc[tl] - s_cnt[tl];
            s_scratch[off + rank[j]] = rec[j];
        }
    }
    __syncthreads();

    // Coalesced copy to global arena.
    unsigned base = s_base;
    for (unsigned i = t; i < total; i += 256) arena[base + i] = s_scratch[i];

    // Emit CHUNK-bounded descriptors per non-empty tile (thread t owns tile t).
    unsigned c = s_cnt[t];
    if (c > 0) {
        unsigned off0 = s_inc[t] - c;
        for (unsigned o = 0; o < c; o += CHUNK) {
            unsigned cc   = (c - o < CHUNK) ? (c - o) : CHUNK;
            unsigned off  = off0 + o;
            unsigned slot = atomicAdd(&desc_cnt[t], 1u);
            if (slot < (unsigned)maxd) {
                desc[(size_t)t * maxd + slot] = make_uint2(base + off, cc);
            } else {
                unsigned k = atomicAdd(&s_ofn, 1u);
                if (k < 64u) { s_of[k][0] = off; s_of[k][1] = cc; }
                else {
                    for (unsigned q = 0; q < cc; q++) {
                        unsigned r = s_scratch[off + q];
                        atomicAdd(&img_direct[r >> 14], (float)(r & 16383u) * (1.0f/16383.0f));
                    }
                }
            }
        }
    }
    __syncthreads();

    // Cooperative (256-wide) flush of overflowed segments.
    unsigned nof = s_ofn < 64u ? s_ofn : 64u;
    for (unsigned k = 0; k < nof; k++) {
        unsigned off = s_of[k][0], cc = s_of[k][1];
        for (unsigned i = t; i < cc; i += 256) {
            unsigned r = s_scratch[off + i];
            atomicAdd(&img_direct[r >> 14], (float)(r & 16383u) * (1.0f/16383.0f));
        }
    }
}

// ================= pass 2: per-tile LDS accumulation, one descriptor per LANE
// 512 threads x 8 splits: each lane walks its own <=CHUNK-record segment with
// an 8-deep unroll -> 512 independent loads in flight per wave per round.
__global__ __launch_bounds__(512) void tile_accum_kernel(
    const unsigned* __restrict__ arena, const uint2* __restrict__ desc,
    const unsigned* __restrict__ desc_cnt, int maxd, float* __restrict__ gimg)
{
    __shared__ float tile[1024];
    const int t   = blockIdx.x;   // tile id
    const int g   = blockIdx.y;   // split group (0..GSPLIT-1)
    const int tid = threadIdx.x;

    for (int i = tid; i < 1024; i += 512) tile[i] = 0.0f;
    __syncthreads();

    unsigned nd = desc_cnt[t];
    if (nd > (unsigned)maxd) nd = (unsigned)maxd;

    const uint2* __restrict__ dbase = desc + (size_t)t * maxd;

    // Thread handles descriptor d = g + (kbase + tid) * GSPLIT.
    for (unsigned kbase = 0; ; kbase += 512) {
        unsigned d = (unsigned)g + (kbase + (unsigned)tid) * GSPLIT;
        bool valid = d < nd;
        if (__ballot(valid) == 0ull) break;   // per-wave uniform exit

        uint2 dd = valid ? dbase[d] : make_uint2(0u, 0u);
        unsigned start = dd.x;
        unsigned cnt   = valid ? dd.y : 0u;

        for (unsigned i0 = 0; ; i0 += 8) {
            if (__ballot(i0 < cnt) == 0ull) break;
            unsigned rcd[8];
            #pragma unroll
            for (int k = 0; k < 8; k++) {
                unsigned ii = i0 + (unsigned)k;
                unsigned cl = (ii < cnt) ? ii : (cnt ? cnt - 1u : 0u);
                rcd[k] = arena[start + cl];
            }
            #pragma unroll
            for (int k = 0; k < 8; k++) {
                unsigned ii = i0 + (unsigned)k;
                if (ii < cnt) {
                    unsigned pix = rcd[k] >> 14;
                    float val = (float)(rcd[k] & 16383u) * (1.0f/16383.0f);
                    unsigned ix = pix & 511u, iy = pix >> 9;
                    unsigned lp = ((iy & 31u) << 5) | (ix & 31u);
                    atomicAdd(&tile[lp], val);   // LDS atomic — per-CU
                }
            }
        }
    }
    __syncthreads();

    // tiles partition the image; (t,g) unique -> plain stores, no atomics
    const unsigned ty = t >> 4, tx = t & 15;
    float* out = gimg + (size_t)g * NPIX;
    for (int i = tid; i < 1024; i += 512) {
        unsigned gy = ty * 32 + (i >> 5);
        unsigned gx = tx * 32 + (i & 31);
        out[gy * IW + gx] = tile[i];
    }
}

__global__ __launch_bounds__(256) void reduce_bin_kernel(
    const float* __restrict__ gimg, float* __restrict__ out)
{
    int i = blockIdx.x * 256 + threadIdx.x;
    float v = out[i];   // direct-flush atomics already landed in out
    #pragma unroll
    for (int g = 0; g < GSPLIT; g++) v += gimg[(size_t)g * NPIX + i];
    out[i] = v;
}

// ================= R7 fallback (ws too small): direct-atomic pipeline
__global__ __launch_bounds__(256) void render_kernel(
    const float* __restrict__ sources, const float* __restrict__ mpts,
    const float* __restrict__ mnrm,    const float* __restrict__ mpos,
    const float* __restrict__ mrot,
    const float* __restrict__ cp1g, const float* __restrict__ cp2g,
    const float* __restrict__ crad, const float* __restrict__ bp1g,
    const float* __restrict__ bp2g, const float* __restrict__ spp,
    const float* __restrict__ spn,  const unsigned* __restrict__ masks,
    float* __restrict__ imgs, int K)
{
    __shared__ float4 s_cyl[NCYL][2];
    __shared__ float4 s_box[NBOX][2];

    const int t  = threadIdx.x;
    const int n  = blockIdx.x * 256 + t;
    const int s0 = blockIdx.y * SPT;
    const int m  = blockIdx.z;

    const long idx = ((long)m * NP + n) * 3;
    float px = mpts[idx+0], py = mpts[idx+1], pz = mpts[idx+2];
    float nx = mnrm[idx+0], ny = mnrm[idx+1], nz = mnrm[idx+2];

    if (t < NCYL) {
        float p1x = cp1g[t*3+0], p1y = cp1g[t*3+1], p1z = cp1g[t*3+2];
        float axx = cp2g[t*3+0] - p1x;
        float axy = cp2g[t*3+1] - p1y;
        float axz = cp2g[t*3+2] - p1z;
        float L   = sqrtf(axx*axx + axy*axy + axz*axz);
        float inv = 1.0f / (L + FEPS);
        float r   = crad[t];
        s_cyl[t][0] = make_float4(p1x, p1y, p1z, L);
        s_cyl[t][1] = make_float4(axx*inv, axy*inv, axz*inv, r*r);
    } else if (t < NCYL + NBOX) {
        int b = t - NCYL;
        s_box[b][0] = make_float4(bp1g[b*3+0], bp1g[b*3+1], bp1g[b*3+2], 0.0f);
        s_box[b][1] = make_float4(bp2g[b*3+0], bp2g[b*3+1], bp2g[b*3+2], 0.0f);
    }
    __syncthreads();

    float R0 = mrot[m*9+0], R1 = mrot[m*9+1], R2 = mrot[m*9+2];
    float R3 = mrot[m*9+3], R4 = mrot[m*9+4], R5 = mrot[m*9+5];
    float R6 = mrot[m*9+6], R7 = mrot[m*9+7], R8 = mrot[m*9+8];
    float posx = mpos[m*3+0], posy = mpos[m*3+1], posz = mpos[m*3+2];
    float sppx = spp[0], sppy = spp[1], sppz = spp[2];
    float spnx = spn[0], spny = spn[1], spnz = spn[2];

    float tpx = R0*px + R1*py + R2*pz + posx;
    float tpy = R3*px + R4*py + R5*pz + posy;
    float tpz = R6*px + R7*py + R8*pz + posz;
    float tnx = R0*nx + R1*ny + R2*nz;
    float tny = R3*nx + R4*ny + R5*nz;
    float tnz = R6*nx + R7*ny + R8*nz;

    float num = (sppx-tpx)*spnx + (sppy-tpy)*spny + (sppz-tpz)*spnz;

    int linb = blockIdx.x + (int)gridDim.x * (blockIdx.y + (int)gridDim.y * blockIdx.z);
    float* __restrict__ img = imgs + (size_t)(linb % K) * NPIX;

    for (int j = 0; j < SPT; j++) {
        const int s = s0 + j;
        float sx = sources[s*3+0], sy = sources[s*3+1], sz = sources[s*3+2];

        float dx = tpx - sx, dy = tpy - sy, dz = tpz - sz;
        float il = frsq(dx*dx + dy*dy + dz*dz);
        dx *= il; dy *= il; dz *= il;
        float ux = -dx, uy = -dy, uz = -dz;

        unsigned pm = masks[(unsigned)m * NS + (unsigned)s];
        pm = __builtin_amdgcn_readfirstlane(pm);
        unsigned cmask = pm & 0xFFFFu;
        unsigned bmask = (pm >> 16) & 0xFFu;

        bool hit = false;

        while (cmask) {
            int c = __builtin_ctz(cmask);
            cmask &= cmask - 1;
            float4 c0 = s_cyl[c][0];
            float4 c1 = s_cyl[c][1];
            float ocx = tpx - c0.x, ocy = tpy - c0.y, ocz = tpz - c0.z;
            float oa  = ocx*c1.x + ocy*c1.y + ocz*c1.z;
            float Cc  = ocx*ocx + ocy*ocy + ocz*ocz - oa*oa - c1.w;
            float ua  = ux*c1.x + uy*c1.y + uz*c1.z;
            float ocu = ux*ocx + uy*ocy + uz*ocz;
            float Bh  = fmaf(-oa, ua, ocu);
            float A   = fmaf(-ua, ua, 1.0f);
            float disc = fmaf(Bh, Bh, -(A*Cc));
            float sq   = fsqrt_(fmaxf(disc, 0.0f));
            float Ah   = A + 0.5f*FEPS;
            float q1   = -Bh - sq;
            float q2   = -Bh + sq;
            float oaA  = oa * Ah;
            float LA   = c0.w * Ah;
            float epsA = FEPS * Ah;
            float ax1A = fmaf(q1, ua, oaA);
            float ax2A = fmaf(q2, ua, oaA);
            bool dpos  = disc > 0.0f;
            hit = hit | (dpos & (q1 > epsA) & (ax1A >= 0.0f) & (ax1A <= LA))
                      | (dpos & (q2 > epsA) & (ax2A >= 0.0f) & (ax2A <= LA));
        }

        if (bmask) {
            float ivx = frcp((fabsf(ux) < FEPS) ? FEPS : ux);
            float ivy = frcp((fabsf(uy) < FEPS) ? FEPS : uy);
            float ivz = frcp((fabsf(uz) < FEPS) ? FEPS : uz);
            while (bmask) {
                int b = __builtin_ctz(bmask);
                bmask &= bmask - 1;
                float4 b1 = s_box[b][0];
                float4 b2 = s_box[b][1];
                float t0x = (b1.x - tpx) * ivx, t1x = (b2.x - tpx) * ivx;
                float t0y = (b1.y - tpy) * ivy, t1y = (b2.y - tpy) * ivy;
                float t0z = (b1.z - tpz) * ivz, t1z = (b2.z - tpz) * ivz;
                float tmin = fmaxf(fmaxf(fminf(t0x,t1x), fminf(t0y,t1y)), fminf(t0z,t1z));
                float tmax = fminf(fminf(fmaxf(t0x,t1x), fmaxf(t0y,t1y)), fmaxf(t0z,t1z));
                hit = hit | (tmax >= fmaxf(tmin, FEPS));
            }
        }

        {
            float dn = dx*tnx + dy*tny + dz*tnz;
            float rx = fmaf(-2.0f*dn, tnx, dx);
            float ry = fmaf(-2.0f*dn, tny, dy);
            float rz = fmaf(-2.0f*dn, tnz, dz);
            float cosv  = fabsf(dn);
            float denom = rx*spnx + ry*spny + rz*spnz;
            float tt = num * frcp(denom + FEPS);
            float qx = fmaf(tt, rx, tpx);
            float qy = fmaf(tt, ry, tpy);
            float fx = (qx + FEXT) * PXSCALE;
            float fy = (qy + FEXT) * PXSCALE;
            float fxf = floorf(fx), fyf = floorf(fy);
            bool inb = (fxf >= 0.0f) & (fxf < (float)IW) & (fyf >= 0.0f) & (fyf < (float)IH)
                       & (!hit);
            if (inb) atomicAdd(&img[(int)fyf * IW + (int)fxf], cosv);
        }
    }
}

__global__ __launch_bounds__(256) void reduce_kernel(
    const float* __restrict__ imgs, int K, float* __restrict__ out)
{
    int i = blockIdx.x * 256 + threadIdx.x;
    float v = 0.0f;
    for (int k = 0; k < K; k++) v += imgs[(size_t)k * NPIX + i];
    out[i] = v;
}

extern "C" void kernel_launch(void* const* d_in, const int* in_sizes, int n_in,
                              void* d_out, int out_size, void* d_ws, size_t ws_size,
                              hipStream_t stream) {
    const float* sources = (const float*)d_in[0];
    const float* mpts    = (const float*)d_in[1];
    const float* mnrm    = (const float*)d_in[2];
    const float* mpos    = (const float*)d_in[3];
    const float* mrot    = (const float*)d_in[4];
    const float* cp1     = (const float*)d_in[5];
    const float* cp2     = (const float*)d_in[6];
    const float* crad    = (const float*)d_in[7];
    const float* bp1     = (const float*)d_in[8];
    const float* bp2     = (const float*)d_in[9];
    const float* spp     = (const float*)d_in[10];
    const float* spn     = (const float*)d_in[11];

    const size_t ARENA_BYTES = (size_t)NM * NS * NP * 4u;            // 64 MiB
    const size_t GIMG_BYTES  = (size_t)GSPLIT * NPIX * 4u;           //  8 MiB
    const size_t CNT_BYTES   = 4096;
    const size_t BND_BYTES   = 1024;
    const size_t MSK_BYTES   = (size_t)NM * NS * 4u;                 // 32 KiB
    const size_t FIXED = ARENA_BYTES + GIMG_BYTES + CNT_BYTES + BND_BYTES + MSK_BYTES;

    // Adaptive descriptor capacity: as large as ws allows, down to 2048.
    int maxd = 0;
    for (int md = 32768; md >= 2048; md >>= 1) {
        if (FIXED + (size_t)NTILE * md * 8u <= ws_size) { maxd = md; break; }
    }

    if (maxd > 0) {
        // ---------- binning pipeline ----------
        char* p = (char*)d_ws;
        unsigned* arena    = (unsigned*)p;                  p += ARENA_BYTES;
        uint2*    desc     = (uint2*)p;                     p += (size_t)NTILE * maxd * 8u;
        float*    gimg     = (float*)p;                     p += GIMG_BYTES;
        unsigned* galloc   = (unsigned*)p;                  // [0] = alloc, [256..] desc_cnt
        unsigned* desc_cnt = galloc + 256;                  p += CNT_BYTES;
        float4*   bounds   = (float4*)p;                    p += BND_BYTES;
        unsigned* masks    = (unsigned*)p;

        hipMemsetAsync(galloc, 0, CNT_BYTES, stream);
        hipMemsetAsync(d_out, 0, (size_t)NPIX * sizeof(float), stream);  // direct-flush target

        mirror_bounds_kernel<<<NM, 256, 0, stream>>>(mpts, mpos, mrot, bounds);
        mask_kernel<<<(NM * NS + 255) / 256, 256, 0, stream>>>(
            sources, cp1, cp2, crad, bp1, bp2, bounds, masks);

        dim3 grid(NP / 256, NS / SPT, NM);   // (8,16,64) = 8192 blocks
        render_bin_kernel<<<grid, 256, 0, stream>>>(
            sources, mpts, mnrm, mpos, mrot, cp1, cp2, crad, bp1, bp2, spp, spn,
            masks, arena, desc, desc_cnt, galloc, (float*)d_out, maxd);

        dim3 grid2(NTILE, GSPLIT);           // 256 tiles x 8 splits, 512 threads
        tile_accum_kernel<<<grid2, 512, 0, stream>>>(arena, desc, desc_cnt, maxd, gimg);

        reduce_bin_kernel<<<NPIX / 256, 256, 0, stream>>>(gimg, (float*)d_out);
    } else {
        // ---------- R7 fallback: direct atomics with K privatized images ----------
        const size_t IMG_BYTES = (size_t)NPIX * sizeof(float);
        const size_t AUX_BYTES = 1024 + (size_t)NM * NS * sizeof(unsigned);
        int K = 0;
        for (int k = 8; k >= 1; k >>= 1) {
            if ((size_t)k * IMG_BYTES + AUX_BYTES <= ws_size) { K = k; break; }
        }
        float* imgs;
        char*  aux;
        if (K >= 1) {
            imgs = (float*)d_ws;
            aux  = (char*)d_ws + (size_t)K * IMG_BYTES;
            hipMemsetAsync(imgs, 0, (size_t)K * IMG_BYTES, stream);
        } else {
            K    = 1;
            imgs = (float*)d_out;
            aux  = (char*)d_ws;
            hipMemsetAsync(imgs, 0, IMG_BYTES, stream);
        }
        float4*   bounds = (float4*)aux;
        unsigned* masks  = (unsigned*)(aux + 1024);

        mirror_bounds_kernel<<<NM, 256, 0, stream>>>(mpts, mpos, mrot, bounds);
        mask_kernel<<<(NM * NS + 255) / 256, 256, 0, stream>>>(
            sources, cp1, cp2, crad, bp1, bp2, bounds, masks);

        dim3 grid(NP / 256, NS / SPT, NM);
        render_kernel<<<grid, 256, 0, stream>>>(sources, mpts, mnrm, mpos, mrot,
                                                cp1, cp2, crad, bp1, bp2, spp, spn,
                                                masks, imgs, K);
        if (imgs != (float*)d_out) {
            reduce_kernel<<<NPIX / 256, 256, 0, stream>>>(imgs, K, (float*)d_out);
        }
    }
}

// Round 12
// 430.596 us; speedup vs baseline: 1.0457x; 1.0457x over previous
//
#include <hip/hip_runtime.h>

// S,P,M=(128,2048,64), NC,NB=(16,8), H,W=512, EXTENT=12, EPS=1e-9
#define NS   128
#define NP   2048
#define NM   64
#define NCYL 16
#define NBOX 8
#define IH   512
#define IW   512
#define NPIX (IH*IW)
#define FEXT 12.0f
#define FEPS 1e-9f
#define PXSCALE ((float)IW / (2.0f * FEXT))
#define PRUNE_MARGIN 0.05f
#define SPT  8      // sources per thread
#define NTILE 256   // 16x16 grid of 32x32-pixel tiles
#define CHUNK 256u  // max records per descriptor

__device__ __forceinline__ float frcp(float x)   { return __builtin_amdgcn_rcpf(x); }
__device__ __forceinline__ float frsq(float x)   { return __builtin_amdgcn_rsqf(x); }
__device__ __forceinline__ float fsqrt_(float x) { return __builtin_amdgcn_sqrtf(x); }
__device__ __forceinline__ float clamp01(float x){ return fminf(fmaxf(x, 0.0f), 1.0f); }

// ---------------- Pre-pass A: per-mirror bounding sphere of transformed points
__global__ __launch_bounds__(256) void mirror_bounds_kernel(
    const float* __restrict__ mpts, const float* __restrict__ mpos,
    const float* __restrict__ mrot, float4* __restrict__ bounds)
{
    const int m = blockIdx.x;
    const int t = threadIdx.x;
    float R0 = mrot[m*9+0], R1 = mrot[m*9+1], R2 = mrot[m*9+2];
    float R3 = mrot[m*9+3], R4 = mrot[m*9+4], R5 = mrot[m*9+5];
    float R6 = mrot[m*9+6], R7 = mrot[m*9+7], R8 = mrot[m*9+8];
    float posx = mpos[m*3+0], posy = mpos[m*3+1], posz = mpos[m*3+2];

    float mnx = 1e30f, mny = 1e30f, mnz = 1e30f;
    float mxx = -1e30f, mxy = -1e30f, mxz = -1e30f;
    for (int i = t; i < NP; i += 256) {
        long id = ((long)m * NP + i) * 3;
        float px = mpts[id+0], py = mpts[id+1], pz = mpts[id+2];
        float tx = R0*px + R1*py + R2*pz + posx;
        float ty = R3*px + R4*py + R5*pz + posy;
        float tz = R6*px + R7*py + R8*pz + posz;
        mnx = fminf(mnx, tx); mny = fminf(mny, ty); mnz = fminf(mnz, tz);
        mxx = fmaxf(mxx, tx); mxy = fmaxf(mxy, ty); mxz = fmaxf(mxz, tz);
    }
    __shared__ float red[6][256];
    red[0][t] = mnx; red[1][t] = mny; red[2][t] = mnz;
    red[3][t] = mxx; red[4][t] = mxy; red[5][t] = mxz;
    __syncthreads();
    for (int off = 128; off > 0; off >>= 1) {
        if (t < off) {
            red[0][t] = fminf(red[0][t], red[0][t+off]);
            red[1][t] = fminf(red[1][t], red[1][t+off]);
            red[2][t] = fminf(red[2][t], red[2][t+off]);
            red[3][t] = fmaxf(red[3][t], red[3][t+off]);
            red[4][t] = fmaxf(red[4][t], red[4][t+off]);
            red[5][t] = fmaxf(red[5][t], red[5][t+off]);
        }
        __syncthreads();
    }
    if (t == 0) {
        float cx = 0.5f*(red[0][0]+red[3][0]);
        float cy = 0.5f*(red[1][0]+red[4][0]);
        float cz = 0.5f*(red[2][0]+red[5][0]);
        float hx = 0.5f*(red[3][0]-red[0][0]);
        float hy = 0.5f*(red[4][0]-red[1][0]);
        float hz = 0.5f*(red[5][0]-red[2][0]);
        float r  = sqrtf(hx*hx + hy*hy + hz*hz);
        bounds[m] = make_float4(cx, cy, cz, r);
    }
}

// ---------------- Pre-pass B: per-(mirror,source) occluder mask (conservative)
__global__ __launch_bounds__(256) void mask_kernel(
    const float* __restrict__ sources,
    const float* __restrict__ cp1g, const float* __restrict__ cp2g,
    const float* __restrict__ crad,
    const float* __restrict__ bp1g, const float* __restrict__ bp2g,
    const float4* __restrict__ bounds, unsigned* __restrict__ masks)
{
    int pair = blockIdx.x * 256 + threadIdx.x;
    if (pair >= NM * NS) return;
    int m = pair / NS;
    int s = pair - m * NS;

    float4 bd = bounds[m];
    float cx = bd.x, cy = bd.y, cz = bd.z;
    float rm = bd.w + PRUNE_MARGIN;
    float sx = sources[s*3+0], sy = sources[s*3+1], sz = sources[s*3+2];

    float d1x = sx - cx, d1y = sy - cy, d1z = sz - cz;
    float a = d1x*d1x + d1y*d1y + d1z*d1z;

    unsigned mask = 0;

    for (int c = 0; c < NCYL; c++) {
        float p2x = cp1g[c*3+0], p2y = cp1g[c*3+1], p2z = cp1g[c*3+2];
        float d2x = cp2g[c*3+0] - p2x, d2y = cp2g[c*3+1] - p2y, d2z = cp2g[c*3+2] - p2z;
        float rx = cx - p2x, ry = cy - p2y, rz = cz - p2z;
        float e = d2x*d2x + d2y*d2y + d2z*d2z;
        float f = d2x*rx + d2y*ry + d2z*rz;
        float cc = d1x*rx + d1y*ry + d1z*rz;
        float b = d1x*d2x + d1y*d2y + d1z*d2z;
        float denom = a*e - b*b;
        float sN = (denom > 1e-6f) ? clamp01((b*f - cc*e) / denom) : 0.0f;
        float tN = (b*sN + f) / e;
        if (tN < 0.0f)      { tN = 0.0f; sN = clamp01(-cc / a); }
        else if (tN > 1.0f) { tN = 1.0f; sN = clamp01((b - cc) / a); }
        float gx = (cx + d1x*sN) - (p2x + d2x*tN);
        float gy = (cy + d1y*sN) - (p2y + d2y*tN);
        float gz = (cz + d1z*sN) - (p2z + d2z*tN);
        float dist2 = gx*gx + gy*gy + gz*gz;
        float thr = crad[c] + rm;
        if (dist2 <= thr*thr) mask |= (1u << c);
    }

    float ivx = 1.0f / ((fabsf(d1x) < FEPS) ? FEPS : d1x);
    float ivy = 1.0f / ((fabsf(d1y) < FEPS) ? FEPS : d1y);
    float ivz = 1.0f / ((fabsf(d1z) < FEPS) ? FEPS : d1z);
    for (int b = 0; b < NBOX; b++) {
        float lx = bp1g[b*3+0] - rm, ly = bp1g[b*3+1] - rm, lz = bp1g[b*3+2] - rm;
        float hx = bp2g[b*3+0] + rm, hy = bp2g[b*3+1] + rm, hz = bp2g[b*3+2] + rm;
        float t0x = (lx - cx) * ivx, t1x = (hx - cx) * ivx;
        float t0y = (ly - cy) * ivy, t1y = (hy - cy) * ivy;
        float t0z = (lz - cz) * ivz, t1z = (hz - cz) * ivz;
        float tmin = fmaxf(fmaxf(fminf(t0x,t1x), fminf(t0y,t1y)), fminf(t0z,t1z));
        float tmax = fminf(fminf(fmaxf(t0x,t1x), fmaxf(t0y,t1y)), fmaxf(t0z,t1z));
        if (fmaxf(tmin, 0.0f) <= fminf(tmax, 1.0f)) mask |= (1u << (16 + b));
    }

    masks[pair] = mask;
}

// ================= BINNING PIPELINE (pass 1): rays -> tile-grouped records
__global__ __launch_bounds__(256) void render_bin_kernel(
    const float* __restrict__ sources, const float* __restrict__ mpts,
    const float* __restrict__ mnrm,    const float* __restrict__ mpos,
    const float* __restrict__ mrot,
    const float* __restrict__ cp1g, const float* __restrict__ cp2g,
    const float* __restrict__ crad, const float* __restrict__ bp1g,
    const float* __restrict__ bp2g, const float* __restrict__ spp,
    const float* __restrict__ spn,  const unsigned* __restrict__ masks,
    unsigned* __restrict__ arena, uint2* __restrict__ desc,
    unsigned* __restrict__ desc_cnt, unsigned* __restrict__ galloc,
    float* __restrict__ img_direct, int maxd)
{
    __shared__ float4 s_cyl[NCYL][2];
    __shared__ float4 s_box[NBOX][2];
    __shared__ unsigned s_cnt[NTILE];
    __shared__ unsigned s_inc[NTILE];
    __shared__ unsigned s_scratch[256 * SPT];
    __shared__ unsigned s_base;
    __shared__ unsigned s_of[64][2];
    __shared__ unsigned s_ofn;

    const int t  = threadIdx.x;
    const int n  = blockIdx.x * 256 + t;
    const int s0 = blockIdx.y * SPT;
    const int m  = blockIdx.z;

    const long idx = ((long)m * NP + n) * 3;
    float px = mpts[idx+0], py = mpts[idx+1], pz = mpts[idx+2];
    float nx = mnrm[idx+0], ny = mnrm[idx+1], nz = mnrm[idx+2];

    s_cnt[t] = 0;   // 256 threads == NTILE
    if (t == 0) s_ofn = 0;
    if (t < NCYL) {
        float p1x = cp1g[t*3+0], p1y = cp1g[t*3+1], p1z = cp1g[t*3+2];
        float axx = cp2g[t*3+0] - p1x;
        float axy = cp2g[t*3+1] - p1y;
        float axz = cp2g[t*3+2] - p1z;
        float L   = sqrtf(axx*axx + axy*axy + axz*axz);
        float inv = 1.0f / (L + FEPS);
        float r   = crad[t];
        s_cyl[t][0] = make_float4(p1x, p1y, p1z, L);
        s_cyl[t][1] = make_float4(axx*inv, axy*inv, axz*inv, r*r);
    } else if (t < NCYL + NBOX) {
        int b = t - NCYL;
        s_box[b][0] = make_float4(bp1g[b*3+0], bp1g[b*3+1], bp1g[b*3+2], 0.0f);
        s_box[b][1] = make_float4(bp2g[b*3+0], bp2g[b*3+1], bp2g[b*3+2], 0.0f);
    }
    __syncthreads();

    float R0 = mrot[m*9+0], R1 = mrot[m*9+1], R2 = mrot[m*9+2];
    float R3 = mrot[m*9+3], R4 = mrot[m*9+4], R5 = mrot[m*9+5];
    float R6 = mrot[m*9+6], R7 = mrot[m*9+7], R8 = mrot[m*9+8];
    float posx = mpos[m*3+0], posy = mpos[m*3+1], posz = mpos[m*3+2];
    float sppx = spp[0], sppy = spp[1], sppz = spp[2];
    float spnx = spn[0], spny = spn[1], spnz = spn[2];

    float tpx = R0*px + R1*py + R2*pz + posx;
    float tpy = R3*px + R4*py + R5*pz + posy;
    float tpz = R6*px + R7*py + R8*pz + posz;
    float tnx = R0*nx + R1*ny + R2*nz;
    float tny = R3*nx + R4*ny + R5*nz;
    float tnz = R6*nx + R7*ny + R8*nz;

    float num = (sppx-tpx)*spnx + (sppy-tpy)*spny + (sppz-tpz)*spnz;

    unsigned rec[SPT];
    unsigned rank[SPT];
    int      tileid[SPT];
    unsigned vmask = 0;

    #pragma unroll
    for (int j = 0; j < SPT; j++) {
        const int s = s0 + j;
        float sx = sources[s*3+0], sy = sources[s*3+1], sz = sources[s*3+2];

        float dx = tpx - sx, dy = tpy - sy, dz = tpz - sz;
        float il = frsq(dx*dx + dy*dy + dz*dz);
        dx *= il; dy *= il; dz *= il;
        float ux = -dx, uy = -dy, uz = -dz;

        unsigned pm = masks[(unsigned)m * NS + (unsigned)s];
        pm = __builtin_amdgcn_readfirstlane(pm);
        unsigned cmask = pm & 0xFFFFu;
        unsigned bmask = (pm >> 16) & 0xFFu;

        bool hit = false;

        while (cmask) {
            int c = __builtin_ctz(cmask);
            cmask &= cmask - 1;
            float4 c0 = s_cyl[c][0];
            float4 c1 = s_cyl[c][1];
            float ocx = tpx - c0.x, ocy = tpy - c0.y, ocz = tpz - c0.z;
            float oa  = ocx*c1.x + ocy*c1.y + ocz*c1.z;
            float Cc  = ocx*ocx + ocy*ocy + ocz*ocz - oa*oa - c1.w;
            float ua  = ux*c1.x + uy*c1.y + uz*c1.z;
            float ocu = ux*ocx + uy*ocy + uz*ocz;
            float Bh  = fmaf(-oa, ua, ocu);
            float A   = fmaf(-ua, ua, 1.0f);
            float disc = fmaf(Bh, Bh, -(A*Cc));
            float sq   = fsqrt_(fmaxf(disc, 0.0f));
            float Ah   = A + 0.5f*FEPS;
            float q1   = -Bh - sq;
            float q2   = -Bh + sq;
            float oaA  = oa * Ah;
            float LA   = c0.w * Ah;
            float epsA = FEPS * Ah;
            float ax1A = fmaf(q1, ua, oaA);
            float ax2A = fmaf(q2, ua, oaA);
            bool dpos  = disc > 0.0f;
            hit = hit | (dpos & (q1 > epsA) & (ax1A >= 0.0f) & (ax1A <= LA))
                      | (dpos & (q2 > epsA) & (ax2A >= 0.0f) & (ax2A <= LA));
        }

        if (bmask) {
            float ivx = frcp((fabsf(ux) < FEPS) ? FEPS : ux);
            float ivy = frcp((fabsf(uy) < FEPS) ? FEPS : uy);
            float ivz = frcp((fabsf(uz) < FEPS) ? FEPS : uz);
            while (bmask) {
                int b = __builtin_ctz(bmask);
                bmask &= bmask - 1;
                float4 b1 = s_box[b][0];
                float4 b2 = s_box[b][1];
                float t0x = (b1.x - tpx) * ivx, t1x = (b2.x - tpx) * ivx;
                float t0y = (b1.y - tpy) * ivy, t1y = (b2.y - tpy) * ivy;
                float t0z = (b1.z - tpz) * ivz, t1z = (b2.z - tpz) * ivz;
                float tmin = fmaxf(fmaxf(fminf(t0x,t1x), fminf(t0y,t1y)), fminf(t0z,t1z));
                float tmax = fminf(fminf(fmaxf(t0x,t1x), fmaxf(t0y,t1y)), fmaxf(t0z,t1z));
                hit = hit | (tmax >= fmaxf(tmin, FEPS));
            }
        }

        float dn = dx*tnx + dy*tny + dz*tnz;
        float rx = fmaf(-2.0f*dn, tnx, dx);
        float ry = fmaf(-2.0f*dn, tny, dy);
        float rz = fmaf(-2.0f*dn, tnz, dz);
        float cosv  = fabsf(dn);
        float denom = rx*spnx + ry*spny + rz*spnz;
        float tt = num * frcp(denom + FEPS);
        float qx = fmaf(tt, rx, tpx);
        float qy = fmaf(tt, ry, tpy);
        float fx = (qx + FEXT) * PXSCALE;
        float fy = (qy + FEXT) * PXSCALE;
        float fxf = floorf(fx), fyf = floorf(fy);
        bool inb = (fxf >= 0.0f) & (fxf < (float)IW) & (fyf >= 0.0f) & (fyf < (float)IH)
                   & (!hit);
        if (inb) {
            int ix = (int)fxf, iy = (int)fyf;
            unsigned pix = (unsigned)(iy * IW + ix);
            unsigned q = (unsigned)(cosv * 16383.0f + 0.5f);
            if (q > 16383u) q = 16383u;
            rec[j]    = (pix << 14) | q;
            int tl    = ((iy >> 5) << 4) | (ix >> 5);
            tileid[j] = tl;
            rank[j]   = atomicAdd(&s_cnt[tl], 1u);
            vmask    |= (1u << j);
        }
    }
    __syncthreads();

    // Inclusive scan of s_cnt -> s_inc (Hillis-Steele, 256 entries).
    s_inc[t] = s_cnt[t];
    __syncthreads();
    for (int st = 1; st < NTILE; st <<= 1) {
        unsigned v = (t >= st) ? s_inc[t - st] : 0u;
        __syncthreads();
        s_inc[t] += v;
        __syncthreads();
    }
    unsigned total = s_inc[NTILE - 1];
    if (t == 0) s_base = total ? atomicAdd(galloc, total) : 0u;
    __syncthreads();

    // Stage records grouped by tile in LDS.
    #pragma unroll
    for (int j = 0; j < SPT; j++) {
        if (vmask & (1u << j)) {
            int tl = tileid[j];
            unsigned off = s_inc[tl] - s_cnt[tl];
            s_scratch[off + rank[j]] = rec[j];
        }
    }
    __syncthreads();

    // Coalesced copy to global arena.
    unsigned base = s_base;
    for (unsigned i = t; i < total; i += 256) arena[base + i] = s_scratch[i];

    // Emit CHUNK-bounded descriptors per non-empty tile (thread t owns tile t).
    unsigned c = s_cnt[t];
    if (c > 0) {
        unsigned off0 = s_inc[t] - c;
        for (unsigned o = 0; o < c; o += CHUNK) {
            unsigned cc   = (c - o < CHUNK) ? (c - o) : CHUNK;
            unsigned off  = off0 + o;
            unsigned slot = atomicAdd(&desc_cnt[t], 1u);
            if (slot < (unsigned)maxd) {
                desc[(size_t)t * maxd + slot] = make_uint2(base + off, cc);
            } else {
                unsigned k = atomicAdd(&s_ofn, 1u);
                if (k < 64u) { s_of[k][0] = off; s_of[k][1] = cc; }
                else {
                    for (unsigned q = 0; q < cc; q++) {
                        unsigned r = s_scratch[off + q];
                        atomicAdd(&img_direct[r >> 14], (float)(r & 16383u) * (1.0f/16383.0f));
                    }
                }
            }
        }
    }
    __syncthreads();

    // Cooperative (256-wide) flush of overflowed segments.
    unsigned nof = s_ofn < 64u ? s_ofn : 64u;
    for (unsigned k = 0; k < nof; k++) {
        unsigned off = s_of[k][0], cc = s_of[k][1];
        for (unsigned i = t; i < cc; i += 256) {
            unsigned r = s_scratch[off + i];
            atomicAdd(&img_direct[r >> 14], (float)(r & 16383u) * (1.0f/16383.0f));
        }
    }
}

// ================= pass 2: per-tile LDS accumulation, 2-stage pipelined,
// wave-per-desc coalesced reads; gsplit blocks per tile (hot-tile CUs x4).
__global__ __launch_bounds__(256) void tile_accum_kernel(
    const unsigned* __restrict__ arena, const uint2* __restrict__ desc,
    const unsigned* __restrict__ desc_cnt, int maxd, int gsplit,
    float* __restrict__ gimg)
{
    __shared__ float tile[1024];
    const int t    = blockIdx.x;   // tile id
    const int g    = blockIdx.y;   // split group (0..gsplit-1)
    const int tid  = threadIdx.x;
    const int wid  = tid >> 6;     // wave id (0..3)
    const int lane = tid & 63;

    for (int i = tid; i < 1024; i += 256) tile[i] = 0.0f;
    __syncthreads();

    unsigned nd = desc_cnt[t];
    if (nd > (unsigned)maxd) nd = (unsigned)maxd;

    const uint2* __restrict__ dbase = desc + (size_t)t * maxd;
    const unsigned ns = (unsigned)gsplit * 4u;   // total wave-streams per tile
    unsigned d = (unsigned)(g * 4 + wid);

    if (d < nd) {
        // ---- 2-stage software pipeline ----
        // State: cur desc (records in regs), next desc (header in regs).
        uint2 dd_cur = dbase[d];
        uint2 dd_nxt = (d + ns < nd) ? dbase[d + ns] : make_uint2(0u, 0u);
        unsigned rcur[4];
        {
            unsigned start = dd_cur.x, cnt = dd_cur.y;
            #pragma unroll
            for (int k = 0; k < 4; k++) {
                unsigned ii = (unsigned)lane + 64u * k;
                unsigned cl = (ii < cnt) ? ii : (cnt ? cnt - 1u : 0u);
                rcur[k] = arena[start + cl];
            }
        }
        while (d < nd) {
            unsigned d2 = d + 2u * ns;
            uint2 dd_n2 = (d2 < nd) ? dbase[d2] : make_uint2(0u, 0u);  // issue desc k+2

            // Issue next desc's record loads (header available from last iter).
            unsigned rnxt[4];
            {
                unsigned start = dd_nxt.x, cnt = dd_nxt.y;
                #pragma unroll
                for (int k = 0; k < 4; k++) {
                    unsigned ii = (unsigned)lane + 64u * k;
                    unsigned cl = (ii < cnt) ? ii : (cnt ? cnt - 1u : 0u);
                    rnxt[k] = arena[start + cl];   // dummy reads arena[0] when cnt==0 (safe)
                }
            }

            // Process current desc's records (already in registers).
            {
                unsigned cnt = dd_cur.y;
                #pragma unroll
                for (int k = 0; k < 4; k++) {
                    unsigned ii = (unsigned)lane + 64u * k;
                    if (ii < cnt) {
                        unsigned pix = rcur[k] >> 14;
                        float val = (float)(rcur[k] & 16383u) * (1.0f/16383.0f);
                        unsigned ix = pix & 511u, iy = pix >> 9;
                        unsigned lp = ((iy & 31u) << 5) | (ix & 31u);
                        atomicAdd(&tile[lp], val);   // LDS atomic — per-CU
                    }
                }
            }

            #pragma unroll
            for (int k = 0; k < 4; k++) rcur[k] = rnxt[k];
            dd_cur = dd_nxt;
            dd_nxt = dd_n2;
            d += ns;
        }
    }
    __syncthreads();

    // tiles partition the image; (t,g) unique -> plain stores, no atomics
    const unsigned ty = t >> 4, tx = t & 15;
    float* out = gimg + (size_t)g * NPIX;
    for (int i = tid; i < 1024; i += 256) {
        unsigned gy = ty * 32 + (i >> 5);
        unsigned gx = tx * 32 + (i & 31);
        out[gy * IW + gx] = tile[i];
    }
}

__global__ __launch_bounds__(256) void reduce_bin_kernel(
    const float* __restrict__ gimg, int gsplit, float* __restrict__ out)
{
    int i = blockIdx.x * 256 + threadIdx.x;
    float v = out[i];   // direct-flush atomics already landed in out
    for (int g = 0; g < gsplit; g++) v += gimg[(size_t)g * NPIX + i];
    out[i] = v;
}

// ================= R7 fallback (ws too small): direct-atomic pipeline
__global__ __launch_bounds__(256) void render_kernel(
    const float* __restrict__ sources, const float* __restrict__ mpts,
    const float* __restrict__ mnrm,    const float* __restrict__ mpos,
    const float* __restrict__ mrot,
    const float* __restrict__ cp1g, const float* __restrict__ cp2g,
    const float* __restrict__ crad, const float* __restrict__ bp1g,
    const float* __restrict__ bp2g, const float* __restrict__ spp,
    const float* __restrict__ spn,  const unsigned* __restrict__ masks,
    float* __restrict__ imgs, int K)
{
    __shared__ float4 s_cyl[NCYL][2];
    __shared__ float4 s_box[NBOX][2];

    const int t  = threadIdx.x;
    const int n  = blockIdx.x * 256 + t;
    const int s0 = blockIdx.y * SPT;
    const int m  = blockIdx.z;

    const long idx = ((long)m * NP + n) * 3;
    float px = mpts[idx+0], py = mpts[idx+1], pz = mpts[idx+2];
    float nx = mnrm[idx+0], ny = mnrm[idx+1], nz = mnrm[idx+2];

    if (t < NCYL) {
        float p1x = cp1g[t*3+0], p1y = cp1g[t*3+1], p1z = cp1g[t*3+2];
        float axx = cp2g[t*3+0] - p1x;
        float axy = cp2g[t*3+1] - p1y;
        float axz = cp2g[t*3+2] - p1z;
        float L   = sqrtf(axx*axx + axy*axy + axz*axz);
        float inv = 1.0f / (L + FEPS);
        float r   = crad[t];
        s_cyl[t][0] = make_float4(p1x, p1y, p1z, L);
        s_cyl[t][1] = make_float4(axx*inv, axy*inv, axz*inv, r*r);
    } else if (t < NCYL + NBOX) {
        int b = t - NCYL;
        s_box[b][0] = make_float4(bp1g[b*3+0], bp1g[b*3+1], bp1g[b*3+2], 0.0f);
        s_box[b][1] = make_float4(bp2g[b*3+0], bp2g[b*3+1], bp2g[b*3+2], 0.0f);
    }
    __syncthreads();

    float R0 = mrot[m*9+0], R1 = mrot[m*9+1], R2 = mrot[m*9+2];
    float R3 = mrot[m*9+3], R4 = mrot[m*9+4], R5 = mrot[m*9+5];
    float R6 = mrot[m*9+6], R7 = mrot[m*9+7], R8 = mrot[m*9+8];
    float posx = mpos[m*3+0], posy = mpos[m*3+1], posz = mpos[m*3+2];
    float sppx = spp[0], sppy = spp[1], sppz = spp[2];
    float spnx = spn[0], spny = spn[1], spnz = spn[2];

    float tpx = R0*px + R1*py + R2*pz + posx;
    float tpy = R3*px + R4*py + R5*pz + posy;
    float tpz = R6*px + R7*py + R8*pz + posz;
    float tnx = R0*nx + R1*ny + R2*nz;
    float tny = R3*nx + R4*ny + R5*nz;
    float tnz = R6*nx + R7*ny + R8*nz;

    float num = (sppx-tpx)*spnx + (sppy-tpy)*spny + (sppz-tpz)*spnz;

    int linb = blockIdx.x + (int)gridDim.x * (blockIdx.y + (int)gridDim.y * blockIdx.z);
    float* __restrict__ img = imgs + (size_t)(linb % K) * NPIX;

    for (int j = 0; j < SPT; j++) {
        const int s = s0 + j;
        float sx = sources[s*3+0], sy = sources[s*3+1], sz = sources[s*3+2];

        float dx = tpx - sx, dy = tpy - sy, dz = tpz - sz;
        float il = frsq(dx*dx + dy*dy + dz*dz);
        dx *= il; dy *= il; dz *= il;
        float ux = -dx, uy = -dy, uz = -dz;

        unsigned pm = masks[(unsigned)m * NS + (unsigned)s];
        pm = __builtin_amdgcn_readfirstlane(pm);
        unsigned cmask = pm & 0xFFFFu;
        unsigned bmask = (pm >> 16) & 0xFFu;

        bool hit = false;

        while (cmask) {
            int c = __builtin_ctz(cmask);
            cmask &= cmask - 1;
            float4 c0 = s_cyl[c][0];
            float4 c1 = s_cyl[c][1];
            float ocx = tpx - c0.x, ocy = tpy - c0.y, ocz = tpz - c0.z;
            float oa  = ocx*c1.x + ocy*c1.y + ocz*c1.z;
            float Cc  = ocx*ocx + ocy*ocy + ocz*ocz - oa*oa - c1.w;
            float ua  = ux*c1.x + uy*c1.y + uz*c1.z;
            float ocu = ux*ocx + uy*ocy + uz*ocz;
            float Bh  = fmaf(-oa, ua, ocu);
            float A   = fmaf(-ua, ua, 1.0f);
            float disc = fmaf(Bh, Bh, -(A*Cc));
            float sq   = fsqrt_(fmaxf(disc, 0.0f));
            float Ah   = A + 0.5f*FEPS;
            float q1   = -Bh - sq;
            float q2   = -Bh + sq;
            float oaA  = oa * Ah;
            float LA   = c0.w * Ah;
            float epsA = FEPS * Ah;
            float ax1A = fmaf(q1, ua, oaA);
            float ax2A = fmaf(q2, ua, oaA);
            bool dpos  = disc > 0.0f;
            hit = hit | (dpos & (q1 > epsA) & (ax1A >= 0.0f) & (ax1A <= LA))
                      | (dpos & (q2 > epsA) & (ax2A >= 0.0f) & (ax2A <= LA));
        }

        if (bmask) {
            float ivx = frcp((fabsf(ux) < FEPS) ? FEPS : ux);
            float ivy = frcp((fabsf(uy) < FEPS) ? FEPS : uy);
            float ivz = frcp((fabsf(uz) < FEPS) ? FEPS : uz);
            while (bmask) {
                int b = __builtin_ctz(bmask);
                bmask &= bmask - 1;
                float4 b1 = s_box[b][0];
                float4 b2 = s_box[b][1];
                float t0x = (b1.x - tpx) * ivx, t1x = (b2.x - tpx) * ivx;
                float t0y = (b1.y - tpy) * ivy, t1y = (b2.y - tpy) * ivy;
                float t0z = (b1.z - tpz) * ivz, t1z = (b2.z - tpz) * ivz;
                float tmin = fmaxf(fmaxf(fminf(t0x,t1x), fminf(t0y,t1y)), fminf(t0z,t1z));
                float tmax = fminf(fminf(fmaxf(t0x,t1x), fmaxf(t0y,t1y)), fmaxf(t0z,t1z));
                hit = hit | (tmax >= fmaxf(tmin, FEPS));
            }
        }

        {
            float dn = dx*tnx + dy*tny + dz*tnz;
            float rx = fmaf(-2.0f*dn, tnx, dx);
            float ry = fmaf(-2.0f*dn, tny, dy);
            float rz = fmaf(-2.0f*dn, tnz, dz);
            float cosv  = fabsf(dn);
            float denom = rx*spnx + ry*spny + rz*spnz;
            float tt = num * frcp(denom + FEPS);
            float qx = fmaf(tt, rx, tpx);
            float qy = fmaf(tt, ry, tpy);
            float fx = (qx + FEXT) * PXSCALE;
            float fy = (qy + FEXT) * PXSCALE;
            float fxf = floorf(fx), fyf = floorf(fy);
            bool inb = (fxf >= 0.0f) & (fxf < (float)IW) & (fyf >= 0.0f) & (fyf < (float)IH)
                       & (!hit);
            if (inb) atomicAdd(&img[(int)fyf * IW + (int)fxf], cosv);
        }
    }
}

__global__ __launch_bounds__(256) void reduce_kernel(
    const float* __restrict__ imgs, int K, float* __restrict__ out)
{
    int i = blockIdx.x * 256 + threadIdx.x;
    float v = 0.0f;
    for (int k = 0; k < K; k++) v += imgs[(size_t)k * NPIX + i];
    out[i] = v;
}

extern "C" void kernel_launch(void* const* d_in, const int* in_sizes, int n_in,
                              void* d_out, int out_size, void* d_ws, size_t ws_size,
                              hipStream_t stream) {
    const float* sources = (const float*)d_in[0];
    const float* mpts    = (const float*)d_in[1];
    const float* mnrm    = (const float*)d_in[2];
    const float* mpos    = (const float*)d_in[3];
    const float* mrot    = (const float*)d_in[4];
    const float* cp1     = (const float*)d_in[5];
    const float* cp2     = (const float*)d_in[6];
    const float* crad    = (const float*)d_in[7];
    const float* bp1     = (const float*)d_in[8];
    const float* bp2     = (const float*)d_in[9];
    const float* spp     = (const float*)d_in[10];
    const float* spn     = (const float*)d_in[11];

    const size_t ARENA_BYTES = (size_t)NM * NS * NP * 4u;            // 64 MiB
    const size_t CNT_BYTES   = 4096;
    const size_t BND_BYTES   = 1024;
    const size_t MSK_BYTES   = (size_t)NM * NS * 4u;                 // 32 KiB

    // Adaptive (gsplit, maxd): prefer gsplit=32 (hot-tile CUs x4), then 16, 8.
    int gsplit = 0, maxd = 0;
    const int gs_opts[3] = {32, 16, 8};
    for (int gi = 0; gi < 3 && gsplit == 0; gi++) {
        int gs = gs_opts[gi];
        size_t fixed = ARENA_BYTES + (size_t)gs * NPIX * 4u + CNT_BYTES + BND_BYTES + MSK_BYTES;
        for (int md = 16384; md >= 2048; md >>= 1) {
            if (fixed + (size_t)NTILE * md * 8u <= ws_size) { gsplit = gs; maxd = md; break; }
        }
    }

    if (maxd > 0) {
        // ---------- binning pipeline ----------
        char* p = (char*)d_ws;
        unsigned* arena    = (unsigned*)p;                  p += ARENA_BYTES;
        uint2*    desc     = (uint2*)p;                     p += (size_t)NTILE * maxd * 8u;
        float*    gimg     = (float*)p;                     p += (size_t)gsplit * NPIX * 4u;
        unsigned* galloc   = (unsigned*)p;                  // [0] = alloc, [256..] desc_cnt
        unsigned* desc_cnt = galloc + 256;                  p += CNT_BYTES;
        float4*   bounds   = (float4*)p;                    p += BND_BYTES;
        unsigned* masks    = (unsigned*)p;

        hipMemsetAsync(galloc, 0, CNT_BYTES, stream);
        hipMemsetAsync(d_out, 0, (size_t)NPIX * sizeof(float), stream);  // direct-flush target

        mirror_bounds_kernel<<<NM, 256, 0, stream>>>(mpts, mpos, mrot, bounds);
        mask_kernel<<<(NM * NS + 255) / 256, 256, 0, stream>>>(
            sources, cp1, cp2, crad, bp1, bp2, bounds, masks);

        dim3 grid(NP / 256, NS / SPT, NM);   // (8,16,64) = 8192 blocks
        render_bin_kernel<<<grid, 256, 0, stream>>>(
            sources, mpts, mnrm, mpos, mrot, cp1, cp2, crad, bp1, bp2, spp, spn,
            masks, arena, desc, desc_cnt, galloc, (float*)d_out, maxd);

        dim3 grid2(NTILE, gsplit);           // 256 tiles x gsplit splits
        tile_accum_kernel<<<grid2, 256, 0, stream>>>(arena, desc, desc_cnt, maxd,
                                                     gsplit, gimg);

        reduce_bin_kernel<<<NPIX / 256, 256, 0, stream>>>(gimg, gsplit, (float*)d_out);
    } else {
        // ---------- R7 fallback: direct atomics with K privatized images ----------
        const size_t IMG_BYTES = (size_t)NPIX * sizeof(float);
        const size_t AUX_BYTES = 1024 + (size_t)NM * NS * sizeof(unsigned);
        int K = 0;
        for (int k = 8; k >= 1; k >>= 1) {
            if ((size_t)k * IMG_BYTES + AUX_BYTES <= ws_size) { K = k; break; }
        }
        float* imgs;
        char*  aux;
        if (K >= 1) {
            imgs = (float*)d_ws;
            aux  = (char*)d_ws + (size_t)K * IMG_BYTES;
            hipMemsetAsync(imgs, 0, (size_t)K * IMG_BYTES, stream);
        } else {
            K    = 1;
            imgs = (float*)d_out;
            aux  = (char*)d_ws;
            hipMemsetAsync(imgs, 0, IMG_BYTES, stream);
        }
        float4*   bounds = (float4*)aux;
        unsigned* masks  = (unsigned*)(aux + 1024);

        mirror_bounds_kernel<<<NM, 256, 0, stream>>>(mpts, mpos, mrot, bounds);
        mask_kernel<<<(NM * NS + 255) / 256, 256, 0, stream>>>(
            sources, cp1, cp2, crad, bp1, bp2, bounds, masks);

        dim3 grid(NP / 256, NS / SPT, NM);
        render_kernel<<<grid, 256, 0, stream>>>(sources, mpts, mnrm, mpos, mrot,
                                                cp1, cp2, crad, bp1, bp2, spp, spn,
                                                masks, imgs, K);
        if (imgs != (float*)d_out) {
            reduce_kernel<<<NPIX / 256, 256, 0, stream>>>(imgs, K, (float*)d_out);
        }
    }
}

// Round 13
// 430.133 us; speedup vs baseline: 1.0468x; 1.0011x over previous
//
#include <hip/hip_runtime.h>

// S,P,M=(128,2048,64), NC,NB=(16,8), H,W=512, EXTENT=12, EPS=1e-9
#define NS   128
#define NP   2048
#define NM   64
#define NCYL 16
#define NBOX 8
#define IH   512
#define IW   512
#define NPIX (IH*IW)
#define FEXT 12.0f
#define FEPS 1e-9f
#define PXSCALE ((float)IW / (2.0f * FEXT))
#define PRUNE_MARGIN 0.05f
#define SPT  8      // sources per thread
#define NTILE 256   // 16x16 grid of 32x32-pixel tiles
#define CHUNK 256u  // max records per descriptor

__device__ __forceinline__ float frcp(float x)   { return __builtin_amdgcn_rcpf(x); }
__device__ __forceinline__ float frsq(float x)   { return __builtin_amdgcn_rsqf(x); }
__device__ __forceinline__ float fsqrt_(float x) { return __builtin_amdgcn_sqrtf(x); }
__device__ __forceinline__ float clamp01(float x){ return fminf(fmaxf(x, 0.0f), 1.0f); }

// ---------------- Pre-pass A: per-mirror bounding sphere of transformed points
__global__ __launch_bounds__(256) void mirror_bounds_kernel(
    const float* __restrict__ mpts, const float* __restrict__ mpos,
    const float* __restrict__ mrot, float4* __restrict__ bounds)
{
    const int m = blockIdx.x;
    const int t = threadIdx.x;
    float R0 = mrot[m*9+0], R1 = mrot[m*9+1], R2 = mrot[m*9+2];
    float R3 = mrot[m*9+3], R4 = mrot[m*9+4], R5 = mrot[m*9+5];
    float R6 = mrot[m*9+6], R7 = mrot[m*9+7], R8 = mrot[m*9+8];
    float posx = mpos[m*3+0], posy = mpos[m*3+1], posz = mpos[m*3+2];

    float mnx = 1e30f, mny = 1e30f, mnz = 1e30f;
    float mxx = -1e30f, mxy = -1e30f, mxz = -1e30f;
    for (int i = t; i < NP; i += 256) {
        long id = ((long)m * NP + i) * 3;
        float px = mpts[id+0], py = mpts[id+1], pz = mpts[id+2];
        float tx = R0*px + R1*py + R2*pz + posx;
        float ty = R3*px + R4*py + R5*pz + posy;
        float tz = R6*px + R7*py + R8*pz + posz;
        mnx = fminf(mnx, tx); mny = fminf(mny, ty); mnz = fminf(mnz, tz);
        mxx = fmaxf(mxx, tx); mxy = fmaxf(mxy, ty); mxz = fmaxf(mxz, tz);
    }
    __shared__ float red[6][256];
    red[0][t] = mnx; red[1][t] = mny; red[2][t] = mnz;
    red[3][t] = mxx; red[4][t] = mxy; red[5][t] = mxz;
    __syncthreads();
    for (int off = 128; off > 0; off >>= 1) {
        if (t < off) {
            red[0][t] = fminf(red[0][t], red[0][t+off]);
            red[1][t] = fminf(red[1][t], red[1][t+off]);
            red[2][t] = fminf(red[2][t], red[2][t+off]);
            red[3][t] = fmaxf(red[3][t], red[3][t+off]);
            red[4][t] = fmaxf(red[4][t], red[4][t+off]);
            red[5][t] = fmaxf(red[5][t], red[5][t+off]);
        }
        __syncthreads();
    }
    if (t == 0) {
        float cx = 0.5f*(red[0][0]+red[3][0]);
        float cy = 0.5f*(red[1][0]+red[4][0]);
        float cz = 0.5f*(red[2][0]+red[5][0]);
        float hx = 0.5f*(red[3][0]-red[0][0]);
        float hy = 0.5f*(red[4][0]-red[1][0]);
        float hz = 0.5f*(red[5][0]-red[2][0]);
        float r  = sqrtf(hx*hx + hy*hy + hz*hz);
        bounds[m] = make_float4(cx, cy, cz, r);
    }
}

// ---------------- Pre-pass B: per-(mirror,source) occluder mask (conservative)
__global__ __launch_bounds__(256) void mask_kernel(
    const float* __restrict__ sources,
    const float* __restrict__ cp1g, const float* __restrict__ cp2g,
    const float* __restrict__ crad,
    const float* __restrict__ bp1g, const float* __restrict__ bp2g,
    const float4* __restrict__ bounds, unsigned* __restrict__ masks)
{
    int pair = blockIdx.x * 256 + threadIdx.x;
    if (pair >= NM * NS) return;
    int m = pair / NS;
    int s = pair - m * NS;

    float4 bd = bounds[m];
    float cx = bd.x, cy = bd.y, cz = bd.z;
    float rm = bd.w + PRUNE_MARGIN;
    float sx = sources[s*3+0], sy = sources[s*3+1], sz = sources[s*3+2];

    float d1x = sx - cx, d1y = sy - cy, d1z = sz - cz;
    float a = d1x*d1x + d1y*d1y + d1z*d1z;

    unsigned mask = 0;

    for (int c = 0; c < NCYL; c++) {
        float p2x = cp1g[c*3+0], p2y = cp1g[c*3+1], p2z = cp1g[c*3+2];
        float d2x = cp2g[c*3+0] - p2x, d2y = cp2g[c*3+1] - p2y, d2z = cp2g[c*3+2] - p2z;
        float rx = cx - p2x, ry = cy - p2y, rz = cz - p2z;
        float e = d2x*d2x + d2y*d2y + d2z*d2z;
        float f = d2x*rx + d2y*ry + d2z*rz;
        float cc = d1x*rx + d1y*ry + d1z*rz;
        float b = d1x*d2x + d1y*d2y + d1z*d2z;
        float denom = a*e - b*b;
        float sN = (denom > 1e-6f) ? clamp01((b*f - cc*e) / denom) : 0.0f;
        float tN = (b*sN + f) / e;
        if (tN < 0.0f)      { tN = 0.0f; sN = clamp01(-cc / a); }
        else if (tN > 1.0f) { tN = 1.0f; sN = clamp01((b - cc) / a); }
        float gx = (cx + d1x*sN) - (p2x + d2x*tN);
        float gy = (cy + d1y*sN) - (p2y + d2y*tN);
        float gz = (cz + d1z*sN) - (p2z + d2z*tN);
        float dist2 = gx*gx + gy*gy + gz*gz;
        float thr = crad[c] + rm;
        if (dist2 <= thr*thr) mask |= (1u << c);
    }

    float ivx = 1.0f / ((fabsf(d1x) < FEPS) ? FEPS : d1x);
    float ivy = 1.0f / ((fabsf(d1y) < FEPS) ? FEPS : d1y);
    float ivz = 1.0f / ((fabsf(d1z) < FEPS) ? FEPS : d1z);
    for (int b = 0; b < NBOX; b++) {
        float lx = bp1g[b*3+0] - rm, ly = bp1g[b*3+1] - rm, lz = bp1g[b*3+2] - rm;
        float hx = bp2g[b*3+0] + rm, hy = bp2g[b*3+1] + rm, hz = bp2g[b*3+2] + rm;
        float t0x = (lx - cx) * ivx, t1x = (hx - cx) * ivx;
        float t0y = (ly - cy) * ivy, t1y = (hy - cy) * ivy;
        float t0z = (lz - cz) * ivz, t1z = (hz - cz) * ivz;
        float tmin = fmaxf(fmaxf(fminf(t0x,t1x), fminf(t0y,t1y)), fminf(t0z,t1z));
        float tmax = fminf(fminf(fmaxf(t0x,t1x), fmaxf(t0y,t1y)), fmaxf(t0z,t1z));
        if (fmaxf(tmin, 0.0f) <= fminf(tmax, 1.0f)) mask |= (1u << (16 + b));
    }

    masks[pair] = mask;
}

// ================= BINNING PIPELINE (pass 1): rays -> tile-grouped records
__global__ __launch_bounds__(256) void render_bin_kernel(
    const float* __restrict__ sources, const float* __restrict__ mpts,
    const float* __restrict__ mnrm,    const float* __restrict__ mpos,
    const float* __restrict__ mrot,
    const float* __restrict__ cp1g, const float* __restrict__ cp2g,
    const float* __restrict__ crad, const float* __restrict__ bp1g,
    const float* __restrict__ bp2g, const float* __restrict__ spp,
    const float* __restrict__ spn,  const unsigned* __restrict__ masks,
    unsigned* __restrict__ arena, uint2* __restrict__ desc,
    unsigned* __restrict__ desc_cnt, unsigned* __restrict__ galloc,
    float* __restrict__ img_direct, int maxd)
{
    __shared__ float4 s_cyl[NCYL][2];
    __shared__ float4 s_box[NBOX][2];
    __shared__ unsigned s_cnt[NTILE];
    __shared__ unsigned s_inc[NTILE];
    __shared__ unsigned s_scratch[256 * SPT];
    __shared__ unsigned s_wsum[4];
    __shared__ unsigned s_base;
    __shared__ unsigned s_of[64][2];
    __shared__ unsigned s_ofn;

    const int t  = threadIdx.x;
    const int n  = blockIdx.x * 256 + t;
    const int s0 = blockIdx.y * SPT;
    const int m  = blockIdx.z;

    const long idx = ((long)m * NP + n) * 3;
    float px = mpts[idx+0], py = mpts[idx+1], pz = mpts[idx+2];
    float nx = mnrm[idx+0], ny = mnrm[idx+1], nz = mnrm[idx+2];

    s_cnt[t] = 0;   // 256 threads == NTILE
    if (t == 0) s_ofn = 0;
    if (t < NCYL) {
        float p1x = cp1g[t*3+0], p1y = cp1g[t*3+1], p1z = cp1g[t*3+2];
        float axx = cp2g[t*3+0] - p1x;
        float axy = cp2g[t*3+1] - p1y;
        float axz = cp2g[t*3+2] - p1z;
        float L   = sqrtf(axx*axx + axy*axy + axz*axz);
        float inv = 1.0f / (L + FEPS);
        float r   = crad[t];
        s_cyl[t][0] = make_float4(p1x, p1y, p1z, L);
        s_cyl[t][1] = make_float4(axx*inv, axy*inv, axz*inv, r*r);
    } else if (t < NCYL + NBOX) {
        int b = t - NCYL;
        s_box[b][0] = make_float4(bp1g[b*3+0], bp1g[b*3+1], bp1g[b*3+2], 0.0f);
        s_box[b][1] = make_float4(bp2g[b*3+0], bp2g[b*3+1], bp2g[b*3+2], 0.0f);
    }
    __syncthreads();

    float R0 = mrot[m*9+0], R1 = mrot[m*9+1], R2 = mrot[m*9+2];
    float R3 = mrot[m*9+3], R4 = mrot[m*9+4], R5 = mrot[m*9+5];
    float R6 = mrot[m*9+6], R7 = mrot[m*9+7], R8 = mrot[m*9+8];
    float posx = mpos[m*3+0], posy = mpos[m*3+1], posz = mpos[m*3+2];
    float sppx = spp[0], sppy = spp[1], sppz = spp[2];
    float spnx = spn[0], spny = spn[1], spnz = spn[2];

    float tpx = R0*px + R1*py + R2*pz + posx;
    float tpy = R3*px + R4*py + R5*pz + posy;
    float tpz = R6*px + R7*py + R8*pz + posz;
    float tnx = R0*nx + R1*ny + R2*nz;
    float tny = R3*nx + R4*ny + R5*nz;
    float tnz = R6*nx + R7*ny + R8*nz;

    float num = (sppx-tpx)*spnx + (sppy-tpy)*spny + (sppz-tpz)*spnz;

    unsigned rec[SPT];
    unsigned rank[SPT];
    int      tileid[SPT];
    unsigned vmask = 0;

    #pragma unroll
    for (int j = 0; j < SPT; j++) {
        const int s = s0 + j;
        float sx = sources[s*3+0], sy = sources[s*3+1], sz = sources[s*3+2];

        float dx = tpx - sx, dy = tpy - sy, dz = tpz - sz;
        float il = frsq(dx*dx + dy*dy + dz*dz);
        dx *= il; dy *= il; dz *= il;
        float ux = -dx, uy = -dy, uz = -dz;

        unsigned pm = masks[(unsigned)m * NS + (unsigned)s];
        pm = __builtin_amdgcn_readfirstlane(pm);
        unsigned cmask = pm & 0xFFFFu;
        unsigned bmask = (pm >> 16) & 0xFFu;

        bool hit = false;

        while (cmask) {
            int c = __builtin_ctz(cmask);
            cmask &= cmask - 1;
            float4 c0 = s_cyl[c][0];
            float4 c1 = s_cyl[c][1];
            float ocx = tpx - c0.x, ocy = tpy - c0.y, ocz = tpz - c0.z;
            float oa  = ocx*c1.x + ocy*c1.y + ocz*c1.z;
            float Cc  = ocx*ocx + ocy*ocy + ocz*ocz - oa*oa - c1.w;
            float ua  = ux*c1.x + uy*c1.y + uz*c1.z;
            float ocu = ux*ocx + uy*ocy + uz*ocz;
            float Bh  = fmaf(-oa, ua, ocu);
            float A   = fmaf(-ua, ua, 1.0f);
            float disc = fmaf(Bh, Bh, -(A*Cc));
            float sq   = fsqrt_(fmaxf(disc, 0.0f));
            float Ah   = A + 0.5f*FEPS;
            float q1   = -Bh - sq;
            float q2   = -Bh + sq;
            float oaA  = oa * Ah;
            float LA   = c0.w * Ah;
            float epsA = FEPS * Ah;
            float ax1A = fmaf(q1, ua, oaA);
            float ax2A = fmaf(q2, ua, oaA);
            bool dpos  = disc > 0.0f;
            hit = hit | (dpos & (q1 > epsA) & (ax1A >= 0.0f) & (ax1A <= LA))
                      | (dpos & (q2 > epsA) & (ax2A >= 0.0f) & (ax2A <= LA));
        }

        if (bmask) {
            float ivx = frcp((fabsf(ux) < FEPS) ? FEPS : ux);
            float ivy = frcp((fabsf(uy) < FEPS) ? FEPS : uy);
            float ivz = frcp((fabsf(uz) < FEPS) ? FEPS : uz);
            while (bmask) {
                int b = __builtin_ctz(bmask);
                bmask &= bmask - 1;
                float4 b1 = s_box[b][0];
                float4 b2 = s_box[b][1];
                float t0x = (b1.x - tpx) * ivx, t1x = (b2.x - tpx) * ivx;
                float t0y = (b1.y - tpy) * ivy, t1y = (b2.y - tpy) * ivy;
                float t0z = (b1.z - tpz) * ivz, t1z = (b2.z - tpz) * ivz;
                float tmin = fmaxf(fmaxf(fminf(t0x,t1x), fminf(t0y,t1y)), fminf(t0z,t1z));
                float tmax = fminf(fminf(fmaxf(t0x,t1x), fmaxf(t0y,t1y)), fmaxf(t0z,t1z));
                hit = hit | (tmax >= fmaxf(tmin, FEPS));
            }
        }

        float dn = dx*tnx + dy*tny + dz*tnz;
        float rx = fmaf(-2.0f*dn, tnx, dx);
        float ry = fmaf(-2.0f*dn, tny, dy);
        float rz = fmaf(-2.0f*dn, tnz, dz);
        float cosv  = fabsf(dn);
        float denom = rx*spnx + ry*spny + rz*spnz;
        float tt = num * frcp(denom + FEPS);
        float qx = fmaf(tt, rx, tpx);
        float qy = fmaf(tt, ry, tpy);
        float fx = (qx + FEXT) * PXSCALE;
        float fy = (qy + FEXT) * PXSCALE;
        float fxf = floorf(fx), fyf = floorf(fy);
        bool inb = (fxf >= 0.0f) & (fxf < (float)IW) & (fyf >= 0.0f) & (fyf < (float)IH)
                   & (!hit);
        if (inb) {
            int ix = (int)fxf, iy = (int)fyf;
            unsigned pix = (unsigned)(iy * IW + ix);
            unsigned q = (unsigned)(cosv * 16383.0f + 0.5f);
            if (q > 16383u) q = 16383u;
            rec[j]    = (pix << 14) | q;
            int tl    = ((iy >> 5) << 4) | (ix >> 5);
            tileid[j] = tl;
            rank[j]   = atomicAdd(&s_cnt[tl], 1u);
            vmask    |= (1u << j);
        }
    }
    __syncthreads();

    // Inclusive scan of s_cnt -> s_inc: shfl wave-scan + 4-entry fixup (2 barriers).
    {
        unsigned v = s_cnt[t];
        const int lane = t & 63;
        #pragma unroll
        for (int off = 1; off < 64; off <<= 1) {
            unsigned x = (unsigned)__shfl_up((int)v, off, 64);
            if (lane >= off) v += x;
        }
        if (lane == 63) s_wsum[t >> 6] = v;
        __syncthreads();
        unsigned w = (unsigned)(t >> 6);
        unsigned basew = 0;
        #pragma unroll
        for (unsigned i = 0; i < 4; i++) if (i < w) basew += s_wsum[i];
        s_inc[t] = v + basew;
        unsigned total_ = s_wsum[0] + s_wsum[1] + s_wsum[2] + s_wsum[3];
        if (t == 0) s_base = total_ ? atomicAdd(galloc, total_) : 0u;
        __syncthreads();
    }
    unsigned total = s_wsum[0] + s_wsum[1] + s_wsum[2] + s_wsum[3];

    // Stage records grouped by tile in LDS.
    #pragma unroll
    for (int j = 0; j < SPT; j++) {
        if (vmask & (1u << j)) {
            int tl = tileid[j];
            unsigned off = s_inc[tl] - s_cnt[tl];
            s_scratch[off + rank[j]] = rec[j];
        }
    }
    __syncthreads();

    // Coalesced copy to global arena.
    unsigned base = s_base;
    for (unsigned i = t; i < total; i += 256) arena[base + i] = s_scratch[i];

    // Emit CHUNK-bounded descriptors per non-empty tile (thread t owns tile t).
    unsigned c = s_cnt[t];
    if (c > 0) {
        unsigned off0 = s_inc[t] - c;
        for (unsigned o = 0; o < c; o += CHUNK) {
            unsigned cc   = (c - o < CHUNK) ? (c - o) : CHUNK;
            unsigned off  = off0 + o;
            unsigned slot = atomicAdd(&desc_cnt[t], 1u);
            if (slot < (unsigned)maxd) {
                desc[(size_t)t * maxd + slot] = make_uint2(base + off, cc);
            } else {
                unsigned k = atomicAdd(&s_ofn, 1u);
                if (k < 64u) { s_of[k][0] = off; s_of[k][1] = cc; }
                else {
                    for (unsigned q = 0; q < cc; q++) {
                        unsigned r = s_scratch[off + q];
                        atomicAdd(&img_direct[r >> 14], (float)(r & 16383u) * (1.0f/16383.0f));
                    }
                }
            }
        }
    }
    __syncthreads();

    // Cooperative (256-wide) flush of overflowed segments.
    unsigned nof = s_ofn < 64u ? s_ofn : 64u;
    for (unsigned k = 0; k < nof; k++) {
        unsigned off = s_of[k][0], cc = s_of[k][1];
        for (unsigned i = t; i < cc; i += 256) {
            unsigned r = s_scratch[off + i];
            atomicAdd(&img_direct[r >> 14], (float)(r & 16383u) * (1.0f/16383.0f));
        }
    }
}

// ================= pass 2: per-tile LDS accumulation, 8-desc batched gather.
// Per wave-iteration: lanes 0..7 fetch 8 descriptor headers in ONE instr,
// broadcast via shfl, then ALL 32 record loads (8 descs x 4/lane = 2048
// records) are issued before any use -> 2 round trips per 8 descriptors.
__global__ __launch_bounds__(256) void tile_accum_kernel(
    const unsigned* __restrict__ arena, const uint2* __restrict__ desc,
    const unsigned* __restrict__ desc_cnt, int maxd, int gsplit,
    float* __restrict__ gimg)
{
    __shared__ float tile[1024];
    const int t    = blockIdx.x;   // tile id
    const int g    = blockIdx.y;   // split group (0..gsplit-1)
    const int tid  = threadIdx.x;
    const int wid  = tid >> 6;     // wave id (0..3)
    const int lane = tid & 63;

    for (int i = tid; i < 1024; i += 256) tile[i] = 0.0f;
    __syncthreads();

    unsigned nd = desc_cnt[t];
    if (nd > (unsigned)maxd) nd = (unsigned)maxd;

    const uint2* __restrict__ dbase = desc + (size_t)t * maxd;
    const unsigned ns = (unsigned)gsplit * 4u;       // wave-stream count per tile
    const unsigned sid = (unsigned)(g * 4 + wid);    // this wave's stream id

    for (unsigned kb = 0; ; kb += 8u) {
        unsigned d0 = sid + kb * ns;
        if (d0 >= nd) break;                         // wave-uniform exit

        // Lane-parallel header fetch (lanes 0..7 each grab one desc).
        unsigned di = sid + (kb + (unsigned)lane) * ns;
        uint2 h = make_uint2(0u, 0u);
        if (lane < 8 && di < nd) h = dbase[di];

        unsigned rcd[8][4];
        unsigned scnt[8], sstart[8];
        #pragma unroll
        for (int j = 0; j < 8; j++) {
            sstart[j] = (unsigned)__shfl((int)h.x, j, 64);
            scnt[j]   = (unsigned)__shfl((int)h.y, j, 64);
        }
        // Issue ALL record loads (32 outstanding per wave).
        #pragma unroll
        for (int j = 0; j < 8; j++) {
            unsigned st = sstart[j], cn = scnt[j];
            #pragma unroll
            for (int k = 0; k < 4; k++) {
                unsigned ii = (unsigned)lane + 64u * k;
                unsigned cl = (ii < cn) ? ii : (cn ? cn - 1u : 0u);
                rcd[j][k] = arena[st + cl];
            }
        }
        // Process.
        #pragma unroll
        for (int j = 0; j < 8; j++) {
            unsigned cn = scnt[j];
            #pragma unroll
            for (int k = 0; k < 4; k++) {
                unsigned ii = (unsigned)lane + 64u * k;
                if (ii < cn) {
                    unsigned pix = rcd[j][k] >> 14;
                    float val = (float)(rcd[j][k] & 16383u) * (1.0f/16383.0f);
                    unsigned ix = pix & 511u, iy = pix >> 9;
                    unsigned lp = ((iy & 31u) << 5) | (ix & 31u);
                    atomicAdd(&tile[lp], val);   // LDS atomic — per-CU
                }
            }
        }
    }
    __syncthreads();

    // tiles partition the image; (t,g) unique -> plain stores, no atomics
    const unsigned ty = t >> 4, tx = t & 15;
    float* out = gimg + (size_t)g * NPIX;
    for (int i = tid; i < 1024; i += 256) {
        unsigned gy = ty * 32 + (i >> 5);
        unsigned gx = tx * 32 + (i & 31);
        out[gy * IW + gx] = tile[i];
    }
}

__global__ __launch_bounds__(256) void reduce_bin_kernel(
    const float4* __restrict__ gimg4, int gsplit, float4* __restrict__ out4)
{
    int i = blockIdx.x * 256 + threadIdx.x;   // over NPIX/4
    float4 v = out4[i];   // direct-flush atomics already landed in out
    for (int g = 0; g < gsplit; g++) {
        float4 a = gimg4[(size_t)g * (NPIX/4) + i];
        v.x += a.x; v.y += a.y; v.z += a.z; v.w += a.w;
    }
    out4[i] = v;
}

// ================= R7 fallback (ws too small): direct-atomic pipeline
__global__ __launch_bounds__(256) void render_kernel(
    const float* __restrict__ sources, const float* __restrict__ mpts,
    const float* __restrict__ mnrm,    const float* __restrict__ mpos,
    const float* __restrict__ mrot,
    const float* __restrict__ cp1g, const float* __restrict__ cp2g,
    const float* __restrict__ crad, const float* __restrict__ bp1g,
    const float* __restrict__ bp2g, const float* __restrict__ spp,
    const float* __restrict__ spn,  const unsigned* __restrict__ masks,
    float* __restrict__ imgs, int K)
{
    __shared__ float4 s_cyl[NCYL][2];
    __shared__ float4 s_box[NBOX][2];

    const int t  = threadIdx.x;
    const int n  = blockIdx.x * 256 + t;
    const int s0 = blockIdx.y * SPT;
    const int m  = blockIdx.z;

    const long idx = ((long)m * NP + n) * 3;
    float px = mpts[idx+0], py = mpts[idx+1], pz = mpts[idx+2];
    float nx = mnrm[idx+0], ny = mnrm[idx+1], nz = mnrm[idx+2];

    if (t < NCYL) {
        float p1x = cp1g[t*3+0], p1y = cp1g[t*3+1], p1z = cp1g[t*3+2];
        float axx = cp2g[t*3+0] - p1x;
        float axy = cp2g[t*3+1] - p1y;
        float axz = cp2g[t*3+2] - p1z;
        float L   = sqrtf(axx*axx + axy*axy + axz*axz);
        float inv = 1.0f / (L + FEPS);
        float r   = crad[t];
        s_cyl[t][0] = make_float4(p1x, p1y, p1z, L);
        s_cyl[t][1] = make_float4(axx*inv, axy*inv, axz*inv, r*r);
    } else if (t < NCYL + NBOX) {
        int b = t - NCYL;
        s_box[b][0] = make_float4(bp1g[b*3+0], bp1g[b*3+1], bp1g[b*3+2], 0.0f);
        s_box[b][1] = make_float4(bp2g[b*3+0], bp2g[b*3+1], bp2g[b*3+2], 0.0f);
    }
    __syncthreads();

    float R0 = mrot[m*9+0], R1 = mrot[m*9+1], R2 = mrot[m*9+2];
    float R3 = mrot[m*9+3], R4 = mrot[m*9+4], R5 = mrot[m*9+5];
    float R6 = mrot[m*9+6], R7 = mrot[m*9+7], R8 = mrot[m*9+8];
    float posx = mpos[m*3+0], posy = mpos[m*3+1], posz = mpos[m*3+2];
    float sppx = spp[0], sppy = spp[1], sppz = spp[2];
    float spnx = spn[0], spny = spn[1], spnz = spn[2];

    float tpx = R0*px + R1*py + R2*pz + posx;
    float tpy = R3*px + R4*py + R5*pz + posy;
    float tpz = R6*px + R7*py + R8*pz + posz;
    float tnx = R0*nx + R1*ny + R2*nz;
    float tny = R3*nx + R4*ny + R5*nz;
    float tnz = R6*nx + R7*ny + R8*nz;

    float num = (sppx-tpx)*spnx + (sppy-tpy)*spny + (sppz-tpz)*spnz;

    int linb = blockIdx.x + (int)gridDim.x * (blockIdx.y + (int)gridDim.y * blockIdx.z);
    float* __restrict__ img = imgs + (size_t)(linb % K) * NPIX;

    for (int j = 0; j < SPT; j++) {
        const int s = s0 + j;
        float sx = sources[s*3+0], sy = sources[s*3+1], sz = sources[s*3+2];

        float dx = tpx - sx, dy = tpy - sy, dz = tpz - sz;
        float il = frsq(dx*dx + dy*dy + dz*dz);
        dx *= il; dy *= il; dz *= il;
        float ux = -dx, uy = -dy, uz = -dz;

        unsigned pm = masks[(unsigned)m * NS + (unsigned)s];
        pm = __builtin_amdgcn_readfirstlane(pm);
        unsigned cmask = pm & 0xFFFFu;
        unsigned bmask = (pm >> 16) & 0xFFu;

        bool hit = false;

        while (cmask) {
            int c = __builtin_ctz(cmask);
            cmask &= cmask - 1;
            float4 c0 = s_cyl[c][0];
            float4 c1 = s_cyl[c][1];
            float ocx = tpx - c0.x, ocy = tpy - c0.y, ocz = tpz - c0.z;
            float oa  = ocx*c1.x + ocy*c1.y + ocz*c1.z;
            float Cc  = ocx*ocx + ocy*ocy + ocz*ocz - oa*oa - c1.w;
            float ua  = ux*c1.x + uy*c1.y + uz*c1.z;
            float ocu = ux*ocx + uy*ocy + uz*ocz;
            float Bh  = fmaf(-oa, ua, ocu);
            float A   = fmaf(-ua, ua, 1.0f);
            float disc = fmaf(Bh, Bh, -(A*Cc));
            float sq   = fsqrt_(fmaxf(disc, 0.0f));
            float Ah   = A + 0.5f*FEPS;
            float q1   = -Bh - sq;
            float q2   = -Bh + sq;
            float oaA  = oa * Ah;
            float LA   = c0.w * Ah;
            float epsA = FEPS * Ah;
            float ax1A = fmaf(q1, ua, oaA);
            float ax2A = fmaf(q2, ua, oaA);
            bool dpos  = disc > 0.0f;
            hit = hit | (dpos & (q1 > epsA) & (ax1A >= 0.0f) & (ax1A <= LA))
                      | (dpos & (q2 > epsA) & (ax2A >= 0.0f) & (ax2A <= LA));
        }

        if (bmask) {
            float ivx = frcp((fabsf(ux) < FEPS) ? FEPS : ux);
            float ivy = frcp((fabsf(uy) < FEPS) ? FEPS : uy);
            float ivz = frcp((fabsf(uz) < FEPS) ? FEPS : uz);
            while (bmask) {
                int b = __builtin_ctz(bmask);
                bmask &= bmask - 1;
                float4 b1 = s_box[b][0];
                float4 b2 = s_box[b][1];
                float t0x = (b1.x - tpx) * ivx, t1x = (b2.x - tpx) * ivx;
                float t0y = (b1.y - tpy) * ivy, t1y = (b2.y - tpy) * ivy;
                float t0z = (b1.z - tpz) * ivz, t1z = (b2.z - tpz) * ivz;
                float tmin = fmaxf(fmaxf(fminf(t0x,t1x), fminf(t0y,t1y)), fminf(t0z,t1z));
                float tmax = fminf(fminf(fmaxf(t0x,t1x), fmaxf(t0y,t1y)), fmaxf(t0z,t1z));
                hit = hit | (tmax >= fmaxf(tmin, FEPS));
            }
        }

        {
            float dn = dx*tnx + dy*tny + dz*tnz;
            float rx = fmaf(-2.0f*dn, tnx, dx);
            float ry = fmaf(-2.0f*dn, tny, dy);
            float rz = fmaf(-2.0f*dn, tnz, dz);
            float cosv  = fabsf(dn);
            float denom = rx*spnx + ry*spny + rz*spnz;
            float tt = num * frcp(denom + FEPS);
            float qx = fmaf(tt, rx, tpx);
            float qy = fmaf(tt, ry, tpy);
            float fx = (qx + FEXT) * PXSCALE;
            float fy = (qy + FEXT) * PXSCALE;
            float fxf = floorf(fx), fyf = floorf(fy);
            bool inb = (fxf >= 0.0f) & (fxf < (float)IW) & (fyf >= 0.0f) & (fyf < (float)IH)
                       & (!hit);
            if (inb) atomicAdd(&img[(int)fyf * IW + (int)fxf], cosv);
        }
    }
}

__global__ __launch_bounds__(256) void reduce_kernel(
    const float* __restrict__ imgs, int K, float* __restrict__ out)
{
    int i = blockIdx.x * 256 + threadIdx.x;
    float v = 0.0f;
    for (int k = 0; k < K; k++) v += imgs[(size_t)k * NPIX + i];
    out[i] = v;
}

extern "C" void kernel_launch(void* const* d_in, const int* in_sizes, int n_in,
                              void* d_out, int out_size, void* d_ws, size_t ws_size,
                              hipStream_t stream) {
    const float* sources = (const float*)d_in[0];
    const float* mpts    = (const float*)d_in[1];
    const float* mnrm    = (const float*)d_in[2];
    const float* mpos    = (const float*)d_in[3];
    const float* mrot    = (const float*)d_in[4];
    const float* cp1     = (const float*)d_in[5];
    const float* cp2     = (const float*)d_in[6];
    const float* crad    = (const float*)d_in[7];
    const float* bp1     = (const float*)d_in[8];
    const float* bp2     = (const float*)d_in[9];
    const float* spp     = (const float*)d_in[10];
    const float* spn     = (const float*)d_in[11];

    const size_t ARENA_BYTES = (size_t)NM * NS * NP * 4u;            // 64 MiB
    const size_t CNT_BYTES   = 4096;
    const size_t BND_BYTES   = 1024;
    const size_t MSK_BYTES   = (size_t)NM * NS * 4u;                 // 32 KiB

    // Adaptive (gsplit, maxd): prefer more hot-tile CUs, then desc capacity.
    int gsplit = 0, maxd = 0;
    const int gs_opts[4] = {64, 32, 16, 8};
    for (int gi = 0; gi < 4 && gsplit == 0; gi++) {
        int gs = gs_opts[gi];
        size_t fixed = ARENA_BYTES + (size_t)gs * NPIX * 4u + CNT_BYTES + BND_BYTES + MSK_BYTES;
        for (int md = 16384; md >= 2048; md >>= 1) {
            if (fixed + (size_t)NTILE * md * 8u <= ws_size) { gsplit = gs; maxd = md; break; }
        }
    }

    if (maxd > 0) {
        // ---------- binning pipeline ----------
        char* p = (char*)d_ws;
        unsigned* arena    = (unsigned*)p;                  p += ARENA_BYTES;
        uint2*    desc     = (uint2*)p;                     p += (size_t)NTILE * maxd * 8u;
        float*    gimg     = (float*)p;                     p += (size_t)gsplit * NPIX * 4u;
        unsigned* galloc   = (unsigned*)p;                  // [0] = alloc, [256..] desc_cnt
        unsigned* desc_cnt = galloc + 256;                  p += CNT_BYTES;
        float4*   bounds   = (float4*)p;                    p += BND_BYTES;
        unsigned* masks    = (unsigned*)p;

        hipMemsetAsync(galloc, 0, CNT_BYTES, stream);
        hipMemsetAsync(d_out, 0, (size_t)NPIX * sizeof(float), stream);  // direct-flush target

        mirror_bounds_kernel<<<NM, 256, 0, stream>>>(mpts, mpos, mrot, bounds);
        mask_kernel<<<(NM * NS + 255) / 256, 256, 0, stream>>>(
            sources, cp1, cp2, crad, bp1, bp2, bounds, masks);

        dim3 grid(NP / 256, NS / SPT, NM);   // (8,16,64) = 8192 blocks
        render_bin_kernel<<<grid, 256, 0, stream>>>(
            sources, mpts, mnrm, mpos, mrot, cp1, cp2, crad, bp1, bp2, spp, spn,
            masks, arena, desc, desc_cnt, galloc, (float*)d_out, maxd);

        dim3 grid2(NTILE, gsplit);           // 256 tiles x gsplit splits
        tile_accum_kernel<<<grid2, 256, 0, stream>>>(arena, desc, desc_cnt, maxd,
                                                     gsplit, gimg);

        reduce_bin_kernel<<<(NPIX/4) / 256, 256, 0, stream>>>(
            (const float4*)gimg, gsplit, (float4*)d_out);
    } else {
        // ---------- R7 fallback: direct atomics with K privatized images ----------
        const size_t IMG_BYTES = (size_t)NPIX * sizeof(float);
        const size_t AUX_BYTES = 1024 + (size_t)NM * NS * sizeof(unsigned);
        int K = 0;
        for (int k = 8; k >= 1; k >>= 1) {
            if ((size_t)k * IMG_BYTES + AUX_BYTES <= ws_size) { K = k; break; }
        }
        float* imgs;
        char*  aux;
        if (K >= 1) {
            imgs = (float*)d_ws;
            aux  = (char*)d_ws + (size_t)K * IMG_BYTES;
            hipMemsetAsync(imgs, 0, (size_t)K * IMG_BYTES, stream);
        } else {
            K    = 1;
            imgs = (float*)d_out;
            aux  = (char*)d_ws;
            hipMemsetAsync(imgs, 0, IMG_BYTES, stream);
        }
        float4*   bounds = (float4*)aux;
        unsigned* masks  = (unsigned*)(aux + 1024);

        mirror_bounds_kernel<<<NM, 256, 0, stream>>>(mpts, mpos, mrot, bounds);
        mask_kernel<<<(NM * NS + 255) / 256, 256, 0, stream>>>(
            sources, cp1, cp2, crad, bp1, bp2, bounds, masks);

        dim3 grid(NP / 256, NS / SPT, NM);
        render_kernel<<<grid, 256, 0, stream>>>(sources, mpts, mnrm, mpos, mrot,
                                                cp1, cp2, crad, bp1, bp2, spp, spn,
                                                masks, imgs, K);
        if (imgs != (float*)d_out) {
            reduce_kernel<<<NPIX / 256, 256, 0, stream>>>(imgs, K, (float*)d_out);
        }
    }
}